// Round 13
// baseline (511.667 us; speedup 1.0000x reference)
//
#include <hip/hip_runtime.h>

#define EPS_LN 1e-5f

typedef __attribute__((ext_vector_type(4))) float f32x4;
typedef __attribute__((ext_vector_type(8))) __bf16 bf16x8;
typedef __attribute__((ext_vector_type(2))) unsigned int u32x2;
typedef unsigned int u32;
typedef unsigned short u16;

__device__ __forceinline__ u16 f2b(float f) {
  unsigned int u = __builtin_bit_cast(unsigned int, f);
  unsigned int r = (u + 0x7FFFu + ((u >> 16) & 1u)) >> 16;
  return (u16)r;
}
__device__ __forceinline__ float b2f(u16 s) {
  unsigned int u = ((unsigned int)s) << 16;
  return __builtin_bit_cast(float, u);
}
__device__ __forceinline__ void splitf(float v, u16& h, u16& l) {
  h = f2b(v); l = f2b(v - b2f(h));
}
__device__ __forceinline__ float gelu_exact(float v) {
  return 0.5f * v * (1.0f + erff(v * 0.70710678118654752440f));
}
// async global->LDS, 16B/lane; LDS dest = wave-uniform base + lane*16
__device__ __forceinline__ void gload16(const void* g, void* l) {
  __builtin_amdgcn_global_load_lds((const __attribute__((address_space(1))) u32*)g,
                                   (__attribute__((address_space(3))) u32*)l, 16, 0, 0);
}
// PV matrix step: D += A*B via v_mfma_f32_16x16x16_bf16 (inline asm).
__device__ __forceinline__ void pv_mfma(f32x4& o, u32x2 a, u32x2 b) {
  asm("s_nop 1\n\tv_mfma_f32_16x16x16_bf16 %0, %1, %2, %0" : "+v"(o) : "v"(a), "v"(b));
}
// flash LDS tile accessor: 64 rows x 64 shorts, XOR-swizzled 16B chunks
__device__ __forceinline__ int fsw(int row, int sc) {
  return row * 64 + ((((sc >> 3) ^ (row & 7))) << 3) + (sc & 7);
}

// ---------------- transpose fp32 [K][N] -> bf16 [N][K] (batched over z) ----
__global__ __launch_bounds__(256) void k_transpose_bf16(
    const float* __restrict__ src, u16* __restrict__ dst, int K, int N)
{
  __shared__ u16 t[64][65];
  long base = (long)blockIdx.z * (long)K * (long)N;
  const float* s = src + base;
  u16* d = dst + base;
  int n0 = blockIdx.x * 64, k0 = blockIdx.y * 64;
  int c = threadIdx.x & 63, r = threadIdx.x >> 6;
#pragma unroll
  for (int i = 0; i < 16; i++) {
    int k = r * 16 + i;
    t[c][k] = f2b(s[(long)(k0 + k) * N + n0 + c]);
  }
  __syncthreads();
#pragma unroll
  for (int i = 0; i < 16; i++) {
    int n = r * 16 + i;
    d[(long)(n0 + n) * K + k0 + c] = t[n][c];
  }
}

// ------------- split-transpose fp32 [K][N] -> bf16 hi/lo [N][K] ------------
__global__ __launch_bounds__(256) void k_split_transpose(
    const float* __restrict__ src, u16* __restrict__ dh,
    u16* __restrict__ dl, int K, int N)
{
  __shared__ float t[64][65];
  int n0 = blockIdx.x * 64, k0 = blockIdx.y * 64;
  int c = threadIdx.x & 63, r4 = threadIdx.x >> 6;
#pragma unroll
  for (int i = 0; i < 16; i++) {
    int k = r4 * 16 + i;
    t[c][k] = src[(long)(k0 + k) * N + n0 + c];
  }
  __syncthreads();
#pragma unroll
  for (int i = 0; i < 16; i++) {
    int n = r4 * 16 + i;
    float v = t[n][c];
    u16 h = f2b(v);
    dh[(long)(n0 + n) * K + k0 + c] = h;
    dl[(long)(n0 + n) * K + k0 + c] = f2b(v - b2f(h));
  }
}

// --- fused kv: sum split-K partials -> split hi/lo -> natural + transposed -
__global__ __launch_bounds__(256) void k_red_kv(
    const float* __restrict__ P, u16* __restrict__ kvh, u16* __restrict__ kvl,
    u16* __restrict__ kvTh, u16* __restrict__ kvTl)
{
  __shared__ u16 th[64][65];
  __shared__ u16 tl[64][65];
  const long MN = 4096L * 1024;
  int bh = blockIdx.y, s0 = blockIdx.x * 64;
  int b = bh >> 4, h = bh & 15;
  int c = threadIdx.x & 63, r = threadIdx.x >> 6;
  long ibase = ((long)b * 2048 + s0) * 1024 + h * 64;
  long obase = (long)bh * 64 * 2048 + s0;
#pragma unroll
  for (int i = 0; i < 16; i++) {
    int k = r * 16 + i;
    long idx = ibase + (long)k * 1024 + c;
    float v = P[idx] + P[MN + idx];
    u16 hh_, ll_; splitf(v, hh_, ll_);
    kvh[idx] = hh_; kvl[idx] = ll_;
    th[c][k] = hh_; tl[c][k] = ll_;
  }
  __syncthreads();
#pragma unroll
  for (int i = 0; i < 16; i++) {
    int n = r * 16 + i;
    kvTh[obase + (long)n * 2048 + c] = th[n][c];
    kvTl[obase + (long)n * 2048 + c] = tl[n][c];
  }
}

// ---------------- LayerNorm: MODE 1 = single bf16, MODE 2 = split hi/lo ----
template<int MODE>
__global__ __launch_bounds__(256) void k_layernorm(
    const float* __restrict__ x, const float* __restrict__ g,
    const float* __restrict__ b, u16* __restrict__ o1, u16* __restrict__ o2)
{
  int row = blockIdx.x, tid = threadIdx.x;
  const float* xr = x + (long)row * 1024;
  float4 v = *(const float4*)&xr[tid * 4];
  float s = v.x + v.y + v.z + v.w;
  float sq = v.x * v.x + v.y * v.y + v.z * v.z + v.w * v.w;
#pragma unroll
  for (int o = 32; o; o >>= 1) { s += __shfl_down(s, o); sq += __shfl_down(sq, o); }
  __shared__ float red[8];
  int wave = tid >> 6, lane = tid & 63;
  if (lane == 0) { red[wave] = s; red[4 + wave] = sq; }
  __syncthreads();
  s  = red[0] + red[1] + red[2] + red[3];
  sq = red[4] + red[5] + red[6] + red[7];
  float mean = s * (1.0f / 1024.0f);
  float var  = sq * (1.0f / 1024.0f) - mean * mean;
  float rs = rsqrtf(var + EPS_LN);
  float4 gg = *(const float4*)&g[tid * 4];
  float4 bb = *(const float4*)&b[tid * 4];
  float ov[4];
  ov[0] = (v.x - mean) * rs * gg.x + bb.x;
  ov[1] = (v.y - mean) * rs * gg.y + bb.y;
  ov[2] = (v.z - mean) * rs * gg.z + bb.z;
  ov[3] = (v.w - mean) * rs * gg.w + bb.w;
  if (MODE == 1) {
    ushort4 o4; o4.x = f2b(ov[0]); o4.y = f2b(ov[1]); o4.z = f2b(ov[2]); o4.w = f2b(ov[3]);
    *(ushort4*)&o1[(long)row * 1024 + tid * 4] = o4;
  } else {
    ushort4 hh, ll;
    splitf(ov[0], hh.x, ll.x); splitf(ov[1], hh.y, ll.y);
    splitf(ov[2], hh.z, ll.z); splitf(ov[3], hh.w, ll.w);
    *(ushort4*)&o1[(long)row * 1024 + tid * 4] = hh;
    *(ushort4*)&o2[(long)row * 1024 + tid * 4] = ll;
  }
}

// ------- split-bf16 3-term MFMA GEMM v2, SPLIT-K x2, swizzled LDS ----------
__global__ __launch_bounds__(256) void k_gemm_bf3(
    const u16* __restrict__ Ah, const u16* __restrict__ Al,
    const u16* __restrict__ Bh, const u16* __restrict__ Bl,
    float* __restrict__ P, int M, int N, int K)
{
  int split = blockIdx.x & 1;
  int bid = blockIdx.x >> 1;
  int nwg = gridDim.x >> 1, cpx = nwg >> 3;
  int wg = (bid & 7) * cpx + (bid >> 3);       // XCD-chunked
  int mm = M >> 7;
  int mb = wg % mm, nb = wg / mm;              // m-fast: B panel pinned per XCD
  long m0 = (long)mb * 128, n0 = (long)nb * 128;
  int K2 = K >> 1;
  int kbase = split * K2;
  __shared__ __align__(16) u16 sA[2][128 * 64];
  __shared__ __align__(16) u16 sB[2][128 * 64];
  int tid = threadIdx.x, lane = tid & 63, w = tid >> 6;
  int wr = w >> 1, wc = w & 1, l15 = lane & 15, l4 = lane >> 4;
  int lr8 = lane >> 3;                         // row within 8-row stripe
  int cl = (lane & 7) ^ lr8;                   // logical chunk this lane stages
  int scol = (cl & 3) * 8;                     // k-chunk col within the half
  const u16* bA = (cl < 4) ? Ah : Al;          // hi or lo source array
  const u16* bB = (cl < 4) ? Bh : Bl;
  long a_off[4], b_off[4];
#pragma unroll
  for (int r = 0; r < 4; r++) {
    int row = w * 32 + r * 8 + lr8;
    a_off[r] = (m0 + row) * (long)K + kbase + scol;
    b_off[r] = (n0 + row) * (long)K + kbase + scol;
  }
  int nt = K2 >> 5;

  f32x4 acc[4][4];
  f32x4 zz = {0.0f, 0.0f, 0.0f, 0.0f};
#pragma unroll
  for (int i = 0; i < 4; i++)
#pragma unroll
    for (int j = 0; j < 4; j++) acc[i][j] = zz;

#define STAGE_BF3(buf, s_) do { long o = (long)(s_) * 32; \
    _Pragma("unroll") \
    for (int r = 0; r < 4; r++) { \
      gload16(&bA[a_off[r] + o], &sA[buf][(w * 32 + r * 8) * 64]); \
      gload16(&bB[b_off[r] + o], &sB[buf][(w * 32 + r * 8) * 64]); \
    } } while (0)

  STAGE_BF3(0, 0);
  __syncthreads();
  int cur = 0;
  for (int s = 0; s < nt; s++) {
    if (s + 1 < nt) STAGE_BF3(cur ^ 1, s + 1);
    bf16x8 ah[4], al[4], bh[4], bl[4];
#pragma unroll
    for (int mi = 0; mi < 4; mi++) {
      int row = wr * 64 + mi * 16 + l15;
      int k7 = l15 & 7;
      ah[mi] = *(const bf16x8*)&sA[cur][row * 64 + ((l4 ^ k7) * 8)];
      al[mi] = *(const bf16x8*)&sA[cur][row * 64 + (((4 + l4) ^ k7) * 8)];
    }
#pragma unroll
    for (int ni = 0; ni < 4; ni++) {
      int row = wc * 64 + ni * 16 + l15;
      int k7 = l15 & 7;
      bh[ni] = *(const bf16x8*)&sB[cur][row * 64 + ((l4 ^ k7) * 8)];
      bl[ni] = *(const bf16x8*)&sB[cur][row * 64 + (((4 + l4) ^ k7) * 8)];
    }
#pragma unroll
    for (int mi = 0; mi < 4; mi++)
#pragma unroll
      for (int ni = 0; ni < 4; ni++) {
        acc[mi][ni] = __builtin_amdgcn_mfma_f32_16x16x32_bf16(ah[mi], bh[ni], acc[mi][ni], 0, 0, 0);
        acc[mi][ni] = __builtin_amdgcn_mfma_f32_16x16x32_bf16(ah[mi], bl[ni], acc[mi][ni], 0, 0, 0);
        acc[mi][ni] = __builtin_amdgcn_mfma_f32_16x16x32_bf16(al[mi], bh[ni], acc[mi][ni], 0, 0, 0);
      }
    __syncthreads();
    cur ^= 1;
  }
#undef STAGE_BF3
  long base = (long)split * M * N;
#pragma unroll
  for (int mi = 0; mi < 4; mi++) {
#pragma unroll
    for (int j = 0; j < 4; j++) {
      long row = m0 + wr * 64 + mi * 16 + l4 * 4 + j;
#pragma unroll
      for (int ni = 0; ni < 4; ni++) {
        long col = n0 + wc * 64 + ni * 16 + l15;
        P[base + row * N + col] = acc[mi][ni][j];
      }
    }
  }
}

// ---- split-K reduces: out = p0 + p1 (+aux), split-bf16 or fp32 ------------
__global__ __launch_bounds__(256) void k_red_split(
    const float* __restrict__ P, u16* __restrict__ Ch, u16* __restrict__ Cl, long MN)
{
  long i = ((long)blockIdx.x * 256 + threadIdx.x) * 4;
  float4 a = *(const float4*)&P[i];
  float4 b = *(const float4*)&P[MN + i];
  ushort4 h, l;
  splitf(a.x + b.x, h.x, l.x); splitf(a.y + b.y, h.y, l.y);
  splitf(a.z + b.z, h.z, l.z); splitf(a.w + b.w, h.w, l.w);
  *(ushort4*)&Ch[i] = h;
  *(ushort4*)&Cl[i] = l;
}

__global__ __launch_bounds__(256) void k_red_resid(
    const float* __restrict__ P, const float* __restrict__ x,
    float* __restrict__ out, long MN)
{
  long i = ((long)blockIdx.x * 256 + threadIdx.x) * 4;
  float4 a = *(const float4*)&P[i];
  float4 b = *(const float4*)&P[MN + i];
  float4 xv = *(const float4*)&x[i];
  float4 r = {a.x + b.x + xv.x, a.y + b.y + xv.y, a.z + b.z + xv.z, a.w + b.w + xv.w};
  *(float4*)&out[i] = r;
}

// ------------- split-bf16 MFMA causal flash attention (v3) ----------------
__global__ __launch_bounds__(256) void k_flash_v3(
    const u16* __restrict__ Qh, const u16* __restrict__ Ql,
    const u16* __restrict__ Kh, const u16* __restrict__ Kl,
    const u16* __restrict__ Th, const u16* __restrict__ Tl,
    u16* __restrict__ Oh, u16* __restrict__ Ol)
{
  int qb = (int)gridDim.y - 1 - (int)blockIdx.y;  // heavy tiles first
  int bh = blockIdx.x;
  int q0 = qb * 64;
  int tid = threadIdx.x, lane = tid & 63, w = tid >> 6;
  int l15 = lane & 15, l4 = lane >> 4;
  __shared__ __align__(16) u16 Qsh[4096], Qsl[4096];
  __shared__ __align__(16) u16 Ksh[2][4096], Ksl[2][4096];
  __shared__ __align__(16) u16 Tsh[2][4096], Tsl[2][4096];
  long rowb = (long)(bh >> 4) * 2048;          // token row base
  int  colo = (bh & 15) * 64;                  // head col offset
  long tbase = (long)bh * 64 * 2048;           // kvT base
  int r8 = lane >> 3;
  int c8s = ((lane & 7) ^ r8) * 8;             // swizzled source chunk (shorts)

#pragma unroll
  for (int k = 0; k < 2; k++) {
    int rr = w * 16 + k * 8;
    long src = (rowb + q0 + rr + r8) * 1024 + colo + c8s;
    gload16(&Qh[src], &Qsh[rr * 64]);
    gload16(&Ql[src], &Qsl[rr * 64]);
  }
#pragma unroll
  for (int k = 0; k < 2; k++) {
    int rr = w * 16 + k * 8;
    long srcK = (rowb + rr + r8) * 1024 + colo + c8s;
    long srcT = tbase + (long)(rr + r8) * 2048 + c8s;
    gload16(&Kh[srcK], &Ksh[0][rr * 64]);
    gload16(&Kl[srcK], &Ksl[0][rr * 64]);
    gload16(&Th[srcT], &Tsh[0][rr * 64]);
    gload16(&Tl[srcT], &Tsl[0][rr * 64]);
  }
  __syncthreads();

  float m = -1e30f, lsum = 0.0f;
  f32x4 o[4];
  f32x4 zz = {0.0f, 0.0f, 0.0f, 0.0f};
#pragma unroll
  for (int nb = 0; nb < 4; nb++) o[nb] = zz;
  int cur = 0;

  for (int kt = 0; kt <= qb; kt++) {
    int k0 = kt * 64;
    if (kt < qb) {
      int kn = k0 + 64, nxt = cur ^ 1;
#pragma unroll
      for (int k = 0; k < 2; k++) {
        int rr = w * 16 + k * 8;
        long srcK = (rowb + kn + rr + r8) * 1024 + colo + c8s;
        long srcT = tbase + (long)(rr + r8) * 2048 + kn + c8s;
        gload16(&Kh[srcK], &Ksh[nxt][rr * 64]);
        gload16(&Kl[srcK], &Ksl[nxt][rr * 64]);
        gload16(&Th[srcT], &Tsh[nxt][rr * 64]);
        gload16(&Tl[srcT], &Tsl[nxt][rr * 64]);
      }
    }
    f32x4 sT[4];
#pragma unroll
    for (int mi = 0; mi < 4; mi++) sT[mi] = zz;
#pragma unroll
    for (int ds = 0; ds < 2; ds++) {
      int qoff = fsw(w * 16 + l15, ds * 32 + l4 * 8);
      bf16x8 qh = *(const bf16x8*)&Qsh[qoff];
      bf16x8 ql = *(const bf16x8*)&Qsl[qoff];
#pragma unroll
      for (int mi = 0; mi < 4; mi++) {
        int koff = fsw(mi * 16 + l15, ds * 32 + l4 * 8);
        bf16x8 kh = *(const bf16x8*)&Ksh[cur][koff];
        bf16x8 kl = *(const bf16x8*)&Ksl[cur][koff];
        sT[mi] = __builtin_amdgcn_mfma_f32_16x16x32_bf16(kh, qh, sT[mi], 0, 0, 0);
        sT[mi] = __builtin_amdgcn_mfma_f32_16x16x32_bf16(kh, ql, sT[mi], 0, 0, 0);
        sT[mi] = __builtin_amdgcn_mfma_f32_16x16x32_bf16(kl, qh, sT[mi], 0, 0, 0);
      }
    }
    bool diag = (kt == qb);
    int qg = q0 + w * 16 + l15;
    float p[4][4];
    float tm = -1e30f;
#pragma unroll
    for (int mi = 0; mi < 4; mi++)
#pragma unroll
      for (int r = 0; r < 4; r++) {
        float v = sT[mi][r] * 0.125f;
        if (diag && (k0 + mi * 16 + l4 * 4 + r > qg)) v = -1e30f;
        p[mi][r] = v; tm = fmaxf(tm, v);
      }
    tm = fmaxf(tm, __shfl_xor(tm, 16));
    tm = fmaxf(tm, __shfl_xor(tm, 32));
    float mn = fmaxf(m, tm);
    float corr = __expf(m - mn);
    m = mn;
    float rs = 0.0f;
#pragma unroll
    for (int mi = 0; mi < 4; mi++)
#pragma unroll
      for (int r = 0; r < 4; r++) {
        float pv = __expf(p[mi][r] - mn);
        p[mi][r] = pv; rs += pv;
      }
    rs += __shfl_xor(rs, 16);
    rs += __shfl_xor(rs, 32);
    lsum = lsum * corr + rs;
    float corrO[4];
#pragma unroll
    for (int r = 0; r < 4; r++) corrO[r] = __shfl(corr, l4 * 4 + r);
#pragma unroll
    for (int nb = 0; nb < 4; nb++)
#pragma unroll
      for (int r = 0; r < 4; r++) o[nb][r] *= corrO[r];
    u32x2 pah[4], pal[4];
#pragma unroll
    for (int mi = 0; mi < 4; mi++) {
      u16 h[4], l[4];
#pragma unroll
      for (int r = 0; r < 4; r++) splitf(p[mi][r], h[r], l[r]);
      pah[mi][0] = (u32)h[0] | ((u32)h[1] << 16);
      pah[mi][1] = (u32)h[2] | ((u32)h[3] << 16);
      pal[mi][0] = (u32)l[0] | ((u32)l[1] << 16);
      pal[mi][1] = (u32)l[2] | ((u32)l[3] << 16);
    }
#pragma unroll
    for (int nb = 0; nb < 4; nb++) {
#pragma unroll
      for (int mi = 0; mi < 4; mi++) {
        int toff = fsw(nb * 16 + l15, mi * 16 + l4 * 4);
        u32x2 vh = *(const u32x2*)&Tsh[cur][toff];
        u32x2 vl = *(const u32x2*)&Tsl[cur][toff];
        pv_mfma(o[nb], pah[mi], vh);
        pv_mfma(o[nb], pah[mi], vl);
        pv_mfma(o[nb], pal[mi], vh);
      }
    }
    __syncthreads();
    cur ^= 1;
  }
  __builtin_amdgcn_sched_barrier(0);
  asm volatile("s_nop 7\n\ts_nop 7" ::: "memory");
  __builtin_amdgcn_sched_barrier(0);
  float inv[4];
#pragma unroll
  for (int r = 0; r < 4; r++) inv[r] = 1.0f / __shfl(lsum, l4 * 4 + r);
#pragma unroll
  for (int nb = 0; nb < 4; nb++)
#pragma unroll
    for (int r = 0; r < 4; r++) {
      long idx = (rowb + q0 + w * 16 + l4 * 4 + r) * 1024 + colo + nb * 16 + l15;
      u16 hh_, ll_; splitf(o[nb][r] * inv[r], hh_, ll_);
      Oh[idx] = hh_; Ol[idx] = ll_;
    }
}

// ---------------- gate: fp32 inline-LN + logits + top2 --------------------
__global__ __launch_bounds__(256) void k_gate(
    const float* __restrict__ x1, const float* __restrict__ g2, const float* __restrict__ b2,
    const float* __restrict__ Wg, const float* __restrict__ bg,
    int* __restrict__ sel, float* __restrict__ wts)
{
  int t = blockIdx.x * 4 + (threadIdx.x >> 6);
  int lane = threadIdx.x & 63;
  const float* xr = x1 + (long)t * 1024;
  float v[16], s = 0.0f, sq = 0.0f;
#pragma unroll
  for (int i = 0; i < 16; i++) { v[i] = xr[lane + 64 * i]; s += v[i]; sq += v[i] * v[i]; }
#pragma unroll
  for (int o = 32; o; o >>= 1) { s += __shfl_xor(s, o); sq += __shfl_xor(sq, o); }
  float mean = s * (1.0f / 1024.0f);
  float var = sq * (1.0f / 1024.0f) - mean * mean;
  float rs = rsqrtf(var + EPS_LN);
  float acc[8];
#pragma unroll
  for (int e = 0; e < 8; e++) acc[e] = 0.0f;
#pragma unroll
  for (int i = 0; i < 16; i++) {
    int d = lane + 64 * i;
    float hh = (v[i] - mean) * rs * g2[d] + b2[d];
    float4 w0 = *(const float4*)&Wg[d * 8];
    float4 w1 = *(const float4*)&Wg[d * 8 + 4];
    acc[0] += hh * w0.x; acc[1] += hh * w0.y; acc[2] += hh * w0.z; acc[3] += hh * w0.w;
    acc[4] += hh * w1.x; acc[5] += hh * w1.y; acc[6] += hh * w1.z; acc[7] += hh * w1.w;
  }
#pragma unroll
  for (int o = 32; o; o >>= 1)
#pragma unroll
    for (int e = 0; e < 8; e++) acc[e] += __shfl_xor(acc[e], o);
  if (lane == 0) {
    float le[8];
#pragma unroll
    for (int e = 0; e < 8; e++) le[e] = acc[e] + bg[e];
    int i0 = 0;
    for (int e = 1; e < 8; e++) if (le[e] > le[i0]) i0 = e;
    int i1 = (i0 == 0) ? 1 : 0;
    for (int e = 0; e < 8; e++) if (e != i0 && le[e] > le[i1]) i1 = e;
    float w0 = 1.0f / (1.0f + __expf(le[i1] - le[i0]));
    sel[2 * t] = i0; sel[2 * t + 1] = i1;
    wts[2 * t] = w0; wts[2 * t + 1] = 1.0f - w0;
  }
}

// ---------------- routing: count / offsets / deterministic scatter --------
__global__ __launch_bounds__(256) void k_count(const int* __restrict__ sel, int* __restrict__ cnt)
{
  int e = blockIdx.x, tid = threadIdx.x;
  int c = 0;
  for (int t = tid; t < 4096; t += 256)
    c += (sel[2 * t] == e) + (sel[2 * t + 1] == e);
#pragma unroll
  for (int o = 32; o; o >>= 1) c += __shfl_down(c, o);
  __shared__ int red[4];
  int wave = tid >> 6, lane = tid & 63;
  if (lane == 0) red[wave] = c;
  __syncthreads();
  if (tid == 0) cnt[e] = red[0] + red[1] + red[2] + red[3];
}

__global__ void k_offsets(const int* __restrict__ cnt, int* __restrict__ offs)
{
  if (threadIdx.x == 0) {
    int a = 0; offs[0] = 0;
    for (int e = 0; e < 8; e++) { a += cnt[e]; offs[e + 1] = a; }
  }
}

__global__ __launch_bounds__(256) void k_scatter(
    const int* __restrict__ sel, const int* __restrict__ offs,
    int* __restrict__ tlist, int* __restrict__ slot_of)
{
  int e = blockIdx.x, tid = threadIdx.x;
  int lane = tid & 63, wave = tid >> 6;
  __shared__ int wsum[4];
  int base = offs[e];
  for (int t0 = 0; t0 < 4096; t0 += 256) {
    int t = t0 + tid;
    int s0 = sel[2 * t], s1 = sel[2 * t + 1];
    bool p = (s0 == e) || (s1 == e);
    int k = (s0 == e) ? 0 : 1;
    unsigned long long mb = __ballot(p);
    int rank = __popcll(mb & ((1ull << lane) - 1ull));
    if (lane == 0) wsum[wave] = __popcll(mb);
    __syncthreads();
    int wbase = 0;
    for (int w = 0; w < wave; w++) wbase += wsum[w];
    if (p) { int idx = base + wbase + rank; tlist[idx] = t; slot_of[2 * t + k] = idx; }
    base += wsum[0] + wsum[1] + wsum[2] + wsum[3];
    __syncthreads();
  }
}

// ------- grouped bf16 MFMA GEMM (r7 loop, flat tile map, exact grid) ------
template<int EPI>
__global__ __launch_bounds__(256) void k_gemm_moe(
    const u16* __restrict__ A, const u16* __restrict__ Bt,
    void* __restrict__ Cout, const float* __restrict__ bias,
    const int* __restrict__ tlist, const int* __restrict__ offs,
    int N, int K, long strideB, int strideBias)
{
  int nwg = gridDim.x;
  int wg0 = ((blockIdx.x & 7) * (nwg >> 3)) + (blockIdx.x >> 3);  // XCD-chunked
  int nn = N >> 7;
  int off_c[9];
#pragma unroll
  for (int e = 0; e <= 8; e++) off_c[e] = offs[e];
  int tile_off[9];
  tile_off[0] = 0;
#pragma unroll
  for (int e = 0; e < 8; e++)
    tile_off[e + 1] = tile_off[e] + (((off_c[e + 1] - off_c[e]) + 127) >> 7) * nn;
  int ntiles = tile_off[8];
  __shared__ __align__(16) u16 lA[2][128 * 64];
  __shared__ __align__(16) u16 lB[2][128 * 64];
  int tid = threadIdx.x, lane = tid & 63, w = tid >> 6;
  int wr = w >> 1, wc = w & 1;
  int l15 = lane & 15, l4 = lane >> 4;
  int lr8 = lane >> 3;                         // 0..7: row within 8-row group
  int csrc = ((lane & 7) ^ lr8) * 8;           // inverse-swizzled src chunk (shorts)
  int nt = K >> 6;

  for (int t = wg0; t < ntiles; t += nwg) {
    int e = 0;
    while (e < 7 && t >= tile_off[e + 1]) e++;
    int lt = t - tile_off[e];
    int r0 = off_c[e], r1 = off_c[e + 1];
    int rbcnt = ((r1 - r0) + 127) >> 7;
    int rbk = lt % rbcnt, nb = lt / rbcnt;     // rb-minor: expert tiles contiguous
    int m0 = r0 + rbk * 128;
    long n0 = (long)nb * 128;
    const u16* B = Bt + (long)e * strideB;
    const float* bvec = bias + (long)e * strideBias;
    u32 asrc[4], bsrc[4];
#pragma unroll
    for (int r = 0; r < 4; r++) {
      int row = w * 32 + r * 8 + lr8;
      int g = m0 + row; if (g > r1 - 1) g = r1 - 1;
      int ar = (EPI == 2) ? tlist[g] : g;
      asrc[r] = (u32)ar * (u32)K + csrc;
      bsrc[r] = (u32)(n0 + row) * (u32)K + csrc;
    }
    f32x4 acc[4][4];
    f32x4 zz = {0.0f, 0.0f, 0.0f, 0.0f};
#pragma unroll
    for (int i = 0; i < 4; i++)
#pragma unroll
      for (int j = 0; j < 4; j++) acc[i][j] = zz;

#define STAGE_MOE(buf, k0_) do { u32 o_ = (k0_); \
    _Pragma("unroll") \
    for (int r = 0; r < 4; r++) { \
      gload16(&A[asrc[r] + o_], &lA[buf][(w * 32 + r * 8) * 64]); \
      gload16(&B[bsrc[r] + o_], &lB[buf][(w * 32 + r * 8) * 64]); \
    } } while (0)

    STAGE_MOE(0, 0);
    __syncthreads();
    int cur = 0;
    for (int s = 0; s < nt; s++) {
      if (s + 1 < nt) STAGE_MOE(cur ^ 1, (u32)(s + 1) * 64);
#pragma unroll
      for (int ks = 0; ks < 2; ks++) {
        bf16x8 af[4], bq[4];
#pragma unroll
        for (int mi = 0; mi < 4; mi++) {
          int row = wr * 64 + mi * 16 + l15;
          af[mi] = *(const bf16x8*)&lA[cur][row * 64 + (((ks * 4 + l4) ^ (l15 & 7)) * 8)];
        }
#pragma unroll
        for (int ni = 0; ni < 4; ni++) {
          int row = wc * 64 + ni * 16 + l15;
          bq[ni] = *(const bf16x8*)&lB[cur][row * 64 + (((ks * 4 + l4) ^ (l15 & 7)) * 8)];
        }
#pragma unroll
        for (int mi = 0; mi < 4; mi++)
#pragma unroll
          for (int ni = 0; ni < 4; ni++)
            acc[mi][ni] = __builtin_amdgcn_mfma_f32_16x16x32_bf16(af[mi], bq[ni], acc[mi][ni], 0, 0, 0);
      }
      __syncthreads();
      cur ^= 1;
    }
#undef STAGE_MOE
#pragma unroll
    for (int mi = 0; mi < 4; mi++) {
#pragma unroll
      for (int j = 0; j < 4; j++) {
        int row = m0 + wr * 64 + mi * 16 + l4 * 4 + j;
        if (row < r1) {
#pragma unroll
          for (int ni = 0; ni < 4; ni++) {
            long col = n0 + wc * 64 + ni * 16 + l15;
            float vv = acc[mi][ni][j] + bvec[col];
            if (EPI == 2) {
              ((u16*)Cout)[(long)row * N + col] = f2b(gelu_exact(vv));
            } else {
              ((float*)Cout)[(long)row * N + col] = vv;
            }
          }
        }
      }
    }
  }
}

// ---------------- combine: out = x1 + w0*oute[s0] + w1*oute[s1] -----------
__global__ __launch_bounds__(256) void k_combine(
    const float* __restrict__ x1, const float* __restrict__ oute,
    const int* __restrict__ slot_of, const float* __restrict__ wts,
    float* __restrict__ out)
{
  int t = blockIdx.x;
  int c = threadIdx.x * 4;
  int s0 = slot_of[2 * t], s1 = slot_of[2 * t + 1];
  float w0 = wts[2 * t], w1 = wts[2 * t + 1];
  float4 a  = *(const float4*)&x1[(long)t * 1024 + c];
  float4 e0 = *(const float4*)&oute[(long)s0 * 1024 + c];
  float4 e1 = *(const float4*)&oute[(long)s1 * 1024 + c];
  float4 r;
  r.x = a.x + w0 * e0.x + w1 * e1.x;
  r.y = a.y + w0 * e0.y + w1 * e1.y;
  r.z = a.z + w0 * e0.z + w1 * e1.z;
  r.w = a.w + w0 * e0.w + w1 * e1.w;
  *(float4*)&out[(long)t * 1024 + c] = r;
}

// ===========================================================================
extern "C" void kernel_launch(void* const* d_in, const int* in_sizes, int n_in,
                              void* d_out, int out_size, void* d_ws, size_t ws_size,
                              hipStream_t stream)
{
  const float* x    = (const float*)d_in[0];
  const float* ln1s = (const float*)d_in[2];
  const float* ln1b = (const float*)d_in[3];
  const float* Wq   = (const float*)d_in[4];
  const float* Wdkv = (const float*)d_in[5];
  const float* Wukv = (const float*)d_in[6];
  const float* Wo   = (const float*)d_in[7];
  const float* ln2s = (const float*)d_in[8];
  const float* ln2b = (const float*)d_in[9];
  const float* Wg   = (const float*)d_in[10];
  const float* bg   = (const float*)d_in[11];
  const float* We1  = (const float*)d_in[12];
  const float* be1  = (const float*)d_in[13];
  const float* We2  = (const float*)d_in[14];
  const float* be2  = (const float*)d_in[15];
  float* out = (float*)d_out;

  char* wp = (char*)d_ws;
  auto take = [&](size_t nbytes) -> void* {
    char* r = wp; wp += (nbytes + 255) & ~(size_t)255; return (void*)r;
  };
  u16* We1t = (u16*)take(8L * 2048 * 1024 * 2);
  u16* We2t = (u16*)take(8L * 1024 * 2048 * 2);
  u16* hh   = (u16*)take(4096L * 1024 * 2);
  u16* hl   = (u16*)take(4096L * 1024 * 2);
  u16* qh   = (u16*)take(4096L * 1024 * 2);
  u16* ql   = (u16*)take(4096L * 1024 * 2);
  u16* kvh  = (u16*)take(4096L * 1024 * 2);
  u16* kvl  = (u16*)take(4096L * 1024 * 2);
  u16* kvTh = (u16*)take(4096L * 1024 * 2);
  u16* kvTl = (u16*)take(4096L * 1024 * 2);
  u16* cbh  = (u16*)take(4096L * 512 * 2);
  u16* cbl  = (u16*)take(4096L * 512 * 2);
  float* x1 = (float*)take(4096L * 1024 * 4);
  u16* hid  = (u16*)take(8192L * 2048 * 2);
  int*   sel   = (int*)take(8192 * 4);
  float* wts   = (float*)take(8192 * 4);
  int*   cnt   = (int*)take(64);
  int*   offs  = (int*)take(64);
  int*   tlist = (int*)take(8192 * 4);
  int*   slot  = (int*)take(8192 * 4);
  // phase-based aliases (lifetimes disjoint on the in-order stream):
  u16* attn_h = hh;                 // hh/hl dead after Wq+Wdkv GEMMs
  u16* attn_l = hl;
  u16* h2bf   = cbh;                // spans cbh+cbl (dead after kv-up GEMM)
  float* oute = (float*)qh;         // spans qh+ql (dead after flash)
  float* Pk   = (float*)We2t;       // split-K partials (32 MB); We2 transposed AFTER
  // split attention weights live in `hid` (dead until k_gemm_moe<2>): 12 MB
  u16* Wqh   = hid;
  u16* Wql   = Wqh   + 1024L * 1024;
  u16* Wdkvh = Wql   + 1024L * 1024;
  u16* Wdkvl = Wdkvh + 512L * 1024;
  u16* Wukvh = Wdkvl + 512L * 1024;
  u16* Wukvl = Wukvh + 1024L * 512;
  u16* Woh   = Wukvl + 1024L * 512;
  u16* Wol   = Woh   + 1024L * 1024;
  if ((size_t)(wp - (char*)d_ws) > ws_size) return;

  dim3 b256(256);
  // attention weights -> split hi/lo bf16, K-major
  k_split_transpose<<<dim3(16, 16), b256, 0, stream>>>(Wq,   Wqh,   Wql,   1024, 1024);
  k_split_transpose<<<dim3(8, 16),  b256, 0, stream>>>(Wdkv, Wdkvh, Wdkvl, 1024, 512);
  k_split_transpose<<<dim3(16, 8),  b256, 0, stream>>>(Wukv, Wukvh, Wukvl, 512, 1024);
  k_split_transpose<<<dim3(16, 16), b256, 0, stream>>>(Wo,   Woh,   Wol,   1024, 1024);
  // attention path (split-bf16 MFMA + split-K2, fp32-equivalent accuracy)
  k_layernorm<2><<<dim3(4096), b256, 0, stream>>>(x, ln1s, ln1b, hh, hl);
  k_gemm_bf3<<<dim3(512), b256, 0, stream>>>(hh, hl, Wqh, Wql, Pk, 4096, 1024, 1024);
  k_red_split<<<dim3(4096), b256, 0, stream>>>(Pk, qh, ql, 4096L * 1024);
  k_gemm_bf3<<<dim3(256), b256, 0, stream>>>(hh, hl, Wdkvh, Wdkvl, Pk, 4096, 512, 1024);
  k_red_split<<<dim3(2048), b256, 0, stream>>>(Pk, cbh, cbl, 4096L * 512);
  k_gemm_bf3<<<dim3(512), b256, 0, stream>>>(cbh, cbl, Wukvh, Wukvl, Pk, 4096, 1024, 512);
  k_red_kv<<<dim3(32, 32), b256, 0, stream>>>(Pk, kvh, kvl, kvTh, kvTl);
  k_flash_v3<<<dim3(32, 32), b256, 0, stream>>>(qh, ql, kvh, kvl, kvTh, kvTl, attn_h, attn_l);
  k_gemm_bf3<<<dim3(512), b256, 0, stream>>>(attn_h, attn_l, Woh, Wol, Pk, 4096, 1024, 1024);
  k_red_resid<<<dim3(4096), b256, 0, stream>>>(Pk, x, x1, 4096L * 1024);
  // MoE
  k_layernorm<1><<<dim3(4096), b256, 0, stream>>>(x1, ln2s, ln2b, h2bf, nullptr);
  k_gate<<<dim3(1024), b256, 0, stream>>>(x1, ln2s, ln2b, Wg, bg, sel, wts);
  k_count<<<dim3(8), b256, 0, stream>>>(sel, cnt);
  k_offsets<<<dim3(1), dim3(64), 0, stream>>>(cnt, offs);
  k_scatter<<<dim3(8), b256, 0, stream>>>(sel, offs, tlist, slot);
  // expert weights -> bf16, K-major (after Pk is dead: Pk aliases We2t)
  k_transpose_bf16<<<dim3(32, 16, 8), b256, 0, stream>>>(We1, We1t, 1024, 2048);
  k_transpose_bf16<<<dim3(16, 32, 8), b256, 0, stream>>>(We2, We2t, 2048, 1024);
  k_gemm_moe<2><<<dim3(1024), b256, 0, stream>>>(h2bf, We1t, hid, be1, tlist, offs,
                                                 2048, 1024, 2048L * 1024, 2048);
  k_gemm_moe<3><<<dim3(512), b256, 0, stream>>>(hid, We2t, oute, be2, tlist, offs,
                                                 1024, 2048, 1024L * 2048, 1024);
  k_combine<<<dim3(4096), b256, 0, stream>>>(x1, oute, slot, wts, out);
}

// Round 14
// 491.900 us; speedup vs baseline: 1.0402x; 1.0402x over previous
//
#include <hip/hip_runtime.h>

#define EPS_LN 1e-5f

typedef __attribute__((ext_vector_type(4))) float f32x4;
typedef __attribute__((ext_vector_type(8))) __bf16 bf16x8;
typedef __attribute__((ext_vector_type(2))) unsigned int u32x2;
typedef unsigned int u32;
typedef unsigned short u16;

__device__ __forceinline__ u16 f2b(float f) {
  unsigned int u = __builtin_bit_cast(unsigned int, f);
  unsigned int r = (u + 0x7FFFu + ((u >> 16) & 1u)) >> 16;
  return (u16)r;
}
__device__ __forceinline__ float b2f(u16 s) {
  unsigned int u = ((unsigned int)s) << 16;
  return __builtin_bit_cast(float, u);
}
__device__ __forceinline__ void splitf(float v, u16& h, u16& l) {
  h = f2b(v); l = f2b(v - b2f(h));
}
__device__ __forceinline__ float gelu_exact(float v) {
  return 0.5f * v * (1.0f + erff(v * 0.70710678118654752440f));
}
// async global->LDS, 16B/lane; LDS dest = wave-uniform base + lane*16
__device__ __forceinline__ void gload16(const void* g, void* l) {
  __builtin_amdgcn_global_load_lds((const __attribute__((address_space(1))) u32*)g,
                                   (__attribute__((address_space(3))) u32*)l, 16, 0, 0);
}
// PV matrix step: D += A*B via v_mfma_f32_16x16x16_bf16 (inline asm).
__device__ __forceinline__ void pv_mfma(f32x4& o, u32x2 a, u32x2 b) {
  asm("s_nop 1\n\tv_mfma_f32_16x16x16_bf16 %0, %1, %2, %0" : "+v"(o) : "v"(a), "v"(b));
}
// flash LDS tile accessor: 64 rows x 64 shorts, XOR-swizzled 16B chunks
__device__ __forceinline__ int fsw(int row, int sc) {
  return row * 64 + ((((sc >> 3) ^ (row & 7))) << 3) + (sc & 7);
}

// ---------------- transpose fp32 [K][N] -> bf16 [N][K] (batched over z) ----
__global__ __launch_bounds__(256) void k_transpose_bf16(
    const float* __restrict__ src, u16* __restrict__ dst, int K, int N)
{
  __shared__ u16 t[64][65];
  long base = (long)blockIdx.z * (long)K * (long)N;
  const float* s = src + base;
  u16* d = dst + base;
  int n0 = blockIdx.x * 64, k0 = blockIdx.y * 64;
  int c = threadIdx.x & 63, r = threadIdx.x >> 6;
#pragma unroll
  for (int i = 0; i < 16; i++) {
    int k = r * 16 + i;
    t[c][k] = f2b(s[(long)(k0 + k) * N + n0 + c]);
  }
  __syncthreads();
#pragma unroll
  for (int i = 0; i < 16; i++) {
    int n = r * 16 + i;
    d[(long)(n0 + n) * K + k0 + c] = t[n][c];
  }
}

// ------------- split-transpose fp32 [K][N] -> bf16 hi/lo [N][K] ------------
__global__ __launch_bounds__(256) void k_split_transpose(
    const float* __restrict__ src, u16* __restrict__ dh,
    u16* __restrict__ dl, int K, int N)
{
  __shared__ float t[64][65];
  int n0 = blockIdx.x * 64, k0 = blockIdx.y * 64;
  int c = threadIdx.x & 63, r4 = threadIdx.x >> 6;
#pragma unroll
  for (int i = 0; i < 16; i++) {
    int k = r4 * 16 + i;
    t[c][k] = src[(long)(k0 + k) * N + n0 + c];
  }
  __syncthreads();
#pragma unroll
  for (int i = 0; i < 16; i++) {
    int n = r4 * 16 + i;
    float v = t[n][c];
    u16 h = f2b(v);
    dh[(long)(n0 + n) * K + k0 + c] = h;
    dl[(long)(n0 + n) * K + k0 + c] = f2b(v - b2f(h));
  }
}

// --- fused kv: sum split-K partials -> split hi/lo -> natural + transposed -
__global__ __launch_bounds__(256) void k_red_kv(
    const float* __restrict__ P, u16* __restrict__ kvh, u16* __restrict__ kvl,
    u16* __restrict__ kvTh, u16* __restrict__ kvTl)
{
  __shared__ u16 th[64][65];
  __shared__ u16 tl[64][65];
  const long MN = 4096L * 1024;
  int bh = blockIdx.y, s0 = blockIdx.x * 64;
  int b = bh >> 4, h = bh & 15;
  int c = threadIdx.x & 63, r = threadIdx.x >> 6;
  long ibase = ((long)b * 2048 + s0) * 1024 + h * 64;
  long obase = (long)bh * 64 * 2048 + s0;
#pragma unroll
  for (int i = 0; i < 16; i++) {
    int k = r * 16 + i;
    long idx = ibase + (long)k * 1024 + c;
    float v = P[idx] + P[MN + idx];
    u16 hh_, ll_; splitf(v, hh_, ll_);
    kvh[idx] = hh_; kvl[idx] = ll_;
    th[c][k] = hh_; tl[c][k] = ll_;
  }
  __syncthreads();
#pragma unroll
  for (int i = 0; i < 16; i++) {
    int n = r * 16 + i;
    kvTh[obase + (long)n * 2048 + c] = th[n][c];
    kvTl[obase + (long)n * 2048 + c] = tl[n][c];
  }
}

// ---------------- LayerNorm: MODE 1 = single bf16, MODE 2 = split hi/lo ----
template<int MODE>
__global__ __launch_bounds__(256) void k_layernorm(
    const float* __restrict__ x, const float* __restrict__ g,
    const float* __restrict__ b, u16* __restrict__ o1, u16* __restrict__ o2)
{
  int row = blockIdx.x, tid = threadIdx.x;
  const float* xr = x + (long)row * 1024;
  float4 v = *(const float4*)&xr[tid * 4];
  float s = v.x + v.y + v.z + v.w;
  float sq = v.x * v.x + v.y * v.y + v.z * v.z + v.w * v.w;
#pragma unroll
  for (int o = 32; o; o >>= 1) { s += __shfl_down(s, o); sq += __shfl_down(sq, o); }
  __shared__ float red[8];
  int wave = tid >> 6, lane = tid & 63;
  if (lane == 0) { red[wave] = s; red[4 + wave] = sq; }
  __syncthreads();
  s  = red[0] + red[1] + red[2] + red[3];
  sq = red[4] + red[5] + red[6] + red[7];
  float mean = s * (1.0f / 1024.0f);
  float var  = sq * (1.0f / 1024.0f) - mean * mean;
  float rs = rsqrtf(var + EPS_LN);
  float4 gg = *(const float4*)&g[tid * 4];
  float4 bb = *(const float4*)&b[tid * 4];
  float ov[4];
  ov[0] = (v.x - mean) * rs * gg.x + bb.x;
  ov[1] = (v.y - mean) * rs * gg.y + bb.y;
  ov[2] = (v.z - mean) * rs * gg.z + bb.z;
  ov[3] = (v.w - mean) * rs * gg.w + bb.w;
  if (MODE == 1) {
    ushort4 o4; o4.x = f2b(ov[0]); o4.y = f2b(ov[1]); o4.z = f2b(ov[2]); o4.w = f2b(ov[3]);
    *(ushort4*)&o1[(long)row * 1024 + tid * 4] = o4;
  } else {
    ushort4 hh, ll;
    splitf(ov[0], hh.x, ll.x); splitf(ov[1], hh.y, ll.y);
    splitf(ov[2], hh.z, ll.z); splitf(ov[3], hh.w, ll.w);
    *(ushort4*)&o1[(long)row * 1024 + tid * 4] = hh;
    *(ushort4*)&o2[(long)row * 1024 + tid * 4] = ll;
  }
}

// ------- split-bf16 3-term MFMA GEMM v2, SPLIT-K x2, swizzled LDS ----------
__global__ __launch_bounds__(256) void k_gemm_bf3(
    const u16* __restrict__ Ah, const u16* __restrict__ Al,
    const u16* __restrict__ Bh, const u16* __restrict__ Bl,
    float* __restrict__ P, int M, int N, int K)
{
  int split = blockIdx.x & 1;
  int bid = blockIdx.x >> 1;
  int nwg = gridDim.x >> 1, cpx = nwg >> 3;
  int wg = (bid & 7) * cpx + (bid >> 3);       // XCD-chunked
  int mm = M >> 7;
  int mb = wg % mm, nb = wg / mm;              // m-fast: B panel pinned per XCD
  long m0 = (long)mb * 128, n0 = (long)nb * 128;
  int K2 = K >> 1;
  int kbase = split * K2;
  __shared__ __align__(16) u16 sA[2][128 * 64];
  __shared__ __align__(16) u16 sB[2][128 * 64];
  int tid = threadIdx.x, lane = tid & 63, w = tid >> 6;
  int wr = w >> 1, wc = w & 1, l15 = lane & 15, l4 = lane >> 4;
  int lr8 = lane >> 3;                         // row within 8-row stripe
  int cl = (lane & 7) ^ lr8;                   // logical chunk this lane stages
  int scol = (cl & 3) * 8;                     // k-chunk col within the half
  const u16* bA = (cl < 4) ? Ah : Al;          // hi or lo source array
  const u16* bB = (cl < 4) ? Bh : Bl;
  long a_off[4], b_off[4];
#pragma unroll
  for (int r = 0; r < 4; r++) {
    int row = w * 32 + r * 8 + lr8;
    a_off[r] = (m0 + row) * (long)K + kbase + scol;
    b_off[r] = (n0 + row) * (long)K + kbase + scol;
  }
  int nt = K2 >> 5;

  f32x4 acc[4][4];
  f32x4 zz = {0.0f, 0.0f, 0.0f, 0.0f};
#pragma unroll
  for (int i = 0; i < 4; i++)
#pragma unroll
    for (int j = 0; j < 4; j++) acc[i][j] = zz;

#define STAGE_BF3(buf, s_) do { long o = (long)(s_) * 32; \
    _Pragma("unroll") \
    for (int r = 0; r < 4; r++) { \
      gload16(&bA[a_off[r] + o], &sA[buf][(w * 32 + r * 8) * 64]); \
      gload16(&bB[b_off[r] + o], &sB[buf][(w * 32 + r * 8) * 64]); \
    } } while (0)

  STAGE_BF3(0, 0);
  __syncthreads();
  int cur = 0;
  for (int s = 0; s < nt; s++) {
    if (s + 1 < nt) STAGE_BF3(cur ^ 1, s + 1);
    bf16x8 ah[4], al[4], bh[4], bl[4];
#pragma unroll
    for (int mi = 0; mi < 4; mi++) {
      int row = wr * 64 + mi * 16 + l15;
      int k7 = l15 & 7;
      ah[mi] = *(const bf16x8*)&sA[cur][row * 64 + ((l4 ^ k7) * 8)];
      al[mi] = *(const bf16x8*)&sA[cur][row * 64 + (((4 + l4) ^ k7) * 8)];
    }
#pragma unroll
    for (int ni = 0; ni < 4; ni++) {
      int row = wc * 64 + ni * 16 + l15;
      int k7 = l15 & 7;
      bh[ni] = *(const bf16x8*)&sB[cur][row * 64 + ((l4 ^ k7) * 8)];
      bl[ni] = *(const bf16x8*)&sB[cur][row * 64 + (((4 + l4) ^ k7) * 8)];
    }
#pragma unroll
    for (int mi = 0; mi < 4; mi++)
#pragma unroll
      for (int ni = 0; ni < 4; ni++) {
        acc[mi][ni] = __builtin_amdgcn_mfma_f32_16x16x32_bf16(ah[mi], bh[ni], acc[mi][ni], 0, 0, 0);
        acc[mi][ni] = __builtin_amdgcn_mfma_f32_16x16x32_bf16(ah[mi], bl[ni], acc[mi][ni], 0, 0, 0);
        acc[mi][ni] = __builtin_amdgcn_mfma_f32_16x16x32_bf16(al[mi], bh[ni], acc[mi][ni], 0, 0, 0);
      }
    __syncthreads();
    cur ^= 1;
  }
#undef STAGE_BF3
  long base = (long)split * M * N;
#pragma unroll
  for (int mi = 0; mi < 4; mi++) {
#pragma unroll
    for (int j = 0; j < 4; j++) {
      long row = m0 + wr * 64 + mi * 16 + l4 * 4 + j;
#pragma unroll
      for (int ni = 0; ni < 4; ni++) {
        long col = n0 + wc * 64 + ni * 16 + l15;
        P[base + row * N + col] = acc[mi][ni][j];
      }
    }
  }
}

// ---- split-K reduces: out = p0 + p1 (+aux), split-bf16 or fp32 ------------
__global__ __launch_bounds__(256) void k_red_split(
    const float* __restrict__ P, u16* __restrict__ Ch, u16* __restrict__ Cl, long MN)
{
  long i = ((long)blockIdx.x * 256 + threadIdx.x) * 4;
  float4 a = *(const float4*)&P[i];
  float4 b = *(const float4*)&P[MN + i];
  ushort4 h, l;
  splitf(a.x + b.x, h.x, l.x); splitf(a.y + b.y, h.y, l.y);
  splitf(a.z + b.z, h.z, l.z); splitf(a.w + b.w, h.w, l.w);
  *(ushort4*)&Ch[i] = h;
  *(ushort4*)&Cl[i] = l;
}

__global__ __launch_bounds__(256) void k_red_resid(
    const float* __restrict__ P, const float* __restrict__ x,
    float* __restrict__ out, long MN)
{
  long i = ((long)blockIdx.x * 256 + threadIdx.x) * 4;
  float4 a = *(const float4*)&P[i];
  float4 b = *(const float4*)&P[MN + i];
  float4 xv = *(const float4*)&x[i];
  float4 r = {a.x + b.x + xv.x, a.y + b.y + xv.y, a.z + b.z + xv.z, a.w + b.w + xv.w};
  *(float4*)&out[i] = r;
}

// ------------- split-bf16 MFMA causal flash attention (v3) ----------------
__global__ __launch_bounds__(256) void k_flash_v3(
    const u16* __restrict__ Qh, const u16* __restrict__ Ql,
    const u16* __restrict__ Kh, const u16* __restrict__ Kl,
    const u16* __restrict__ Th, const u16* __restrict__ Tl,
    u16* __restrict__ Oh, u16* __restrict__ Ol)
{
  int qb = (int)gridDim.y - 1 - (int)blockIdx.y;  // heavy tiles first
  int bh = blockIdx.x;
  int q0 = qb * 64;
  int tid = threadIdx.x, lane = tid & 63, w = tid >> 6;
  int l15 = lane & 15, l4 = lane >> 4;
  __shared__ __align__(16) u16 Qsh[4096], Qsl[4096];
  __shared__ __align__(16) u16 Ksh[2][4096], Ksl[2][4096];
  __shared__ __align__(16) u16 Tsh[2][4096], Tsl[2][4096];
  long rowb = (long)(bh >> 4) * 2048;          // token row base
  int  colo = (bh & 15) * 64;                  // head col offset
  long tbase = (long)bh * 64 * 2048;           // kvT base
  int r8 = lane >> 3;
  int c8s = ((lane & 7) ^ r8) * 8;             // swizzled source chunk (shorts)

#pragma unroll
  for (int k = 0; k < 2; k++) {
    int rr = w * 16 + k * 8;
    long src = (rowb + q0 + rr + r8) * 1024 + colo + c8s;
    gload16(&Qh[src], &Qsh[rr * 64]);
    gload16(&Ql[src], &Qsl[rr * 64]);
  }
#pragma unroll
  for (int k = 0; k < 2; k++) {
    int rr = w * 16 + k * 8;
    long srcK = (rowb + rr + r8) * 1024 + colo + c8s;
    long srcT = tbase + (long)(rr + r8) * 2048 + c8s;
    gload16(&Kh[srcK], &Ksh[0][rr * 64]);
    gload16(&Kl[srcK], &Ksl[0][rr * 64]);
    gload16(&Th[srcT], &Tsh[0][rr * 64]);
    gload16(&Tl[srcT], &Tsl[0][rr * 64]);
  }
  __syncthreads();

  float m = -1e30f, lsum = 0.0f;
  f32x4 o[4];
  f32x4 zz = {0.0f, 0.0f, 0.0f, 0.0f};
#pragma unroll
  for (int nb = 0; nb < 4; nb++) o[nb] = zz;
  int cur = 0;

  for (int kt = 0; kt <= qb; kt++) {
    int k0 = kt * 64;
    if (kt < qb) {
      int kn = k0 + 64, nxt = cur ^ 1;
#pragma unroll
      for (int k = 0; k < 2; k++) {
        int rr = w * 16 + k * 8;
        long srcK = (rowb + kn + rr + r8) * 1024 + colo + c8s;
        long srcT = tbase + (long)(rr + r8) * 2048 + kn + c8s;
        gload16(&Kh[srcK], &Ksh[nxt][rr * 64]);
        gload16(&Kl[srcK], &Ksl[nxt][rr * 64]);
        gload16(&Th[srcT], &Tsh[nxt][rr * 64]);
        gload16(&Tl[srcT], &Tsl[nxt][rr * 64]);
      }
    }
    f32x4 sT[4];
#pragma unroll
    for (int mi = 0; mi < 4; mi++) sT[mi] = zz;
#pragma unroll
    for (int ds = 0; ds < 2; ds++) {
      int qoff = fsw(w * 16 + l15, ds * 32 + l4 * 8);
      bf16x8 qh = *(const bf16x8*)&Qsh[qoff];
      bf16x8 ql = *(const bf16x8*)&Qsl[qoff];
#pragma unroll
      for (int mi = 0; mi < 4; mi++) {
        int koff = fsw(mi * 16 + l15, ds * 32 + l4 * 8);
        bf16x8 kh = *(const bf16x8*)&Ksh[cur][koff];
        bf16x8 kl = *(const bf16x8*)&Ksl[cur][koff];
        sT[mi] = __builtin_amdgcn_mfma_f32_16x16x32_bf16(kh, qh, sT[mi], 0, 0, 0);
        sT[mi] = __builtin_amdgcn_mfma_f32_16x16x32_bf16(kh, ql, sT[mi], 0, 0, 0);
        sT[mi] = __builtin_amdgcn_mfma_f32_16x16x32_bf16(kl, qh, sT[mi], 0, 0, 0);
      }
    }
    bool diag = (kt == qb);
    int qg = q0 + w * 16 + l15;
    float p[4][4];
    float tm = -1e30f;
#pragma unroll
    for (int mi = 0; mi < 4; mi++)
#pragma unroll
      for (int r = 0; r < 4; r++) {
        float v = sT[mi][r] * 0.125f;
        if (diag && (k0 + mi * 16 + l4 * 4 + r > qg)) v = -1e30f;
        p[mi][r] = v; tm = fmaxf(tm, v);
      }
    tm = fmaxf(tm, __shfl_xor(tm, 16));
    tm = fmaxf(tm, __shfl_xor(tm, 32));
    float mn = fmaxf(m, tm);
    float corr = __expf(m - mn);
    m = mn;
    float rs = 0.0f;
#pragma unroll
    for (int mi = 0; mi < 4; mi++)
#pragma unroll
      for (int r = 0; r < 4; r++) {
        float pv = __expf(p[mi][r] - mn);
        p[mi][r] = pv; rs += pv;
      }
    rs += __shfl_xor(rs, 16);
    rs += __shfl_xor(rs, 32);
    lsum = lsum * corr + rs;
    float corrO[4];
#pragma unroll
    for (int r = 0; r < 4; r++) corrO[r] = __shfl(corr, l4 * 4 + r);
#pragma unroll
    for (int nb = 0; nb < 4; nb++)
#pragma unroll
      for (int r = 0; r < 4; r++) o[nb][r] *= corrO[r];
    u32x2 pah[4], pal[4];
#pragma unroll
    for (int mi = 0; mi < 4; mi++) {
      u16 h[4], l[4];
#pragma unroll
      for (int r = 0; r < 4; r++) splitf(p[mi][r], h[r], l[r]);
      pah[mi][0] = (u32)h[0] | ((u32)h[1] << 16);
      pah[mi][1] = (u32)h[2] | ((u32)h[3] << 16);
      pal[mi][0] = (u32)l[0] | ((u32)l[1] << 16);
      pal[mi][1] = (u32)l[2] | ((u32)l[3] << 16);
    }
#pragma unroll
    for (int nb = 0; nb < 4; nb++) {
#pragma unroll
      for (int mi = 0; mi < 4; mi++) {
        int toff = fsw(nb * 16 + l15, mi * 16 + l4 * 4);
        u32x2 vh = *(const u32x2*)&Tsh[cur][toff];
        u32x2 vl = *(const u32x2*)&Tsl[cur][toff];
        pv_mfma(o[nb], pah[mi], vh);
        pv_mfma(o[nb], pah[mi], vl);
        pv_mfma(o[nb], pal[mi], vh);
      }
    }
    __syncthreads();
    cur ^= 1;
  }
  __builtin_amdgcn_sched_barrier(0);
  asm volatile("s_nop 7\n\ts_nop 7" ::: "memory");
  __builtin_amdgcn_sched_barrier(0);
  float inv[4];
#pragma unroll
  for (int r = 0; r < 4; r++) inv[r] = 1.0f / __shfl(lsum, l4 * 4 + r);
#pragma unroll
  for (int nb = 0; nb < 4; nb++)
#pragma unroll
    for (int r = 0; r < 4; r++) {
      long idx = (rowb + q0 + w * 16 + l4 * 4 + r) * 1024 + colo + nb * 16 + l15;
      u16 hh_, ll_; splitf(o[nb][r] * inv[r], hh_, ll_);
      Oh[idx] = hh_; Ol[idx] = ll_;
    }
}

// ---------------- gate: fp32 inline-LN + logits + top2 --------------------
__global__ __launch_bounds__(256) void k_gate(
    const float* __restrict__ x1, const float* __restrict__ g2, const float* __restrict__ b2,
    const float* __restrict__ Wg, const float* __restrict__ bg,
    int* __restrict__ sel, float* __restrict__ wts)
{
  int t = blockIdx.x * 4 + (threadIdx.x >> 6);
  int lane = threadIdx.x & 63;
  const float* xr = x1 + (long)t * 1024;
  float v[16], s = 0.0f, sq = 0.0f;
#pragma unroll
  for (int i = 0; i < 16; i++) { v[i] = xr[lane + 64 * i]; s += v[i]; sq += v[i] * v[i]; }
#pragma unroll
  for (int o = 32; o; o >>= 1) { s += __shfl_xor(s, o); sq += __shfl_xor(sq, o); }
  float mean = s * (1.0f / 1024.0f);
  float var = sq * (1.0f / 1024.0f) - mean * mean;
  float rs = rsqrtf(var + EPS_LN);
  float acc[8];
#pragma unroll
  for (int e = 0; e < 8; e++) acc[e] = 0.0f;
#pragma unroll
  for (int i = 0; i < 16; i++) {
    int d = lane + 64 * i;
    float hh = (v[i] - mean) * rs * g2[d] + b2[d];
    float4 w0 = *(const float4*)&Wg[d * 8];
    float4 w1 = *(const float4*)&Wg[d * 8 + 4];
    acc[0] += hh * w0.x; acc[1] += hh * w0.y; acc[2] += hh * w0.z; acc[3] += hh * w0.w;
    acc[4] += hh * w1.x; acc[5] += hh * w1.y; acc[6] += hh * w1.z; acc[7] += hh * w1.w;
  }
#pragma unroll
  for (int o = 32; o; o >>= 1)
#pragma unroll
    for (int e = 0; e < 8; e++) acc[e] += __shfl_xor(acc[e], o);
  if (lane == 0) {
    float le[8];
#pragma unroll
    for (int e = 0; e < 8; e++) le[e] = acc[e] + bg[e];
    int i0 = 0;
    for (int e = 1; e < 8; e++) if (le[e] > le[i0]) i0 = e;
    int i1 = (i0 == 0) ? 1 : 0;
    for (int e = 0; e < 8; e++) if (e != i0 && le[e] > le[i1]) i1 = e;
    float w0 = 1.0f / (1.0f + __expf(le[i1] - le[i0]));
    sel[2 * t] = i0; sel[2 * t + 1] = i1;
    wts[2 * t] = w0; wts[2 * t + 1] = 1.0f - w0;
  }
}

// ---------------- routing: count / offsets / deterministic scatter --------
__global__ __launch_bounds__(256) void k_count(const int* __restrict__ sel, int* __restrict__ cnt)
{
  int e = blockIdx.x, tid = threadIdx.x;
  int c = 0;
  for (int t = tid; t < 4096; t += 256)
    c += (sel[2 * t] == e) + (sel[2 * t + 1] == e);
#pragma unroll
  for (int o = 32; o; o >>= 1) c += __shfl_down(c, o);
  __shared__ int red[4];
  int wave = tid >> 6, lane = tid & 63;
  if (lane == 0) red[wave] = c;
  __syncthreads();
  if (tid == 0) cnt[e] = red[0] + red[1] + red[2] + red[3];
}

__global__ void k_offsets(const int* __restrict__ cnt, int* __restrict__ offs)
{
  if (threadIdx.x == 0) {
    int a = 0; offs[0] = 0;
    for (int e = 0; e < 8; e++) { a += cnt[e]; offs[e + 1] = a; }
  }
}

__global__ __launch_bounds__(256) void k_scatter(
    const int* __restrict__ sel, const int* __restrict__ offs,
    int* __restrict__ tlist, int* __restrict__ slot_of)
{
  int e = blockIdx.x, tid = threadIdx.x;
  int lane = tid & 63, wave = tid >> 6;
  __shared__ int wsum[4];
  int base = offs[e];
  for (int t0 = 0; t0 < 4096; t0 += 256) {
    int t = t0 + tid;
    int s0 = sel[2 * t], s1 = sel[2 * t + 1];
    bool p = (s0 == e) || (s1 == e);
    int k = (s0 == e) ? 0 : 1;
    unsigned long long mb = __ballot(p);
    int rank = __popcll(mb & ((1ull << lane) - 1ull));
    if (lane == 0) wsum[wave] = __popcll(mb);
    __syncthreads();
    int wbase = 0;
    for (int w = 0; w < wave; w++) wbase += wsum[w];
    if (p) { int idx = base + wbase + rank; tlist[idx] = t; slot_of[2 * t + k] = idx; }
    base += wsum[0] + wsum[1] + wsum[2] + wsum[3];
    __syncthreads();
  }
}

// ------- grouped bf16 MFMA GEMM (round-7/12 proven): BK=64, swizzled ------
template<int EPI>
__global__ __launch_bounds__(256) void k_gemm_moe(
    const u16* __restrict__ A, const u16* __restrict__ Bt,
    void* __restrict__ Cout, const float* __restrict__ bias,
    const int* __restrict__ tlist, const int* __restrict__ offs,
    int N, int K, long strideB, int strideBias)
{
  int e = blockIdx.x & 7, slot = blockIdx.x >> 3;
  int r0 = offs[e], r1 = offs[e + 1];
  int rows = r1 - r0;
  if (rows <= 0) return;
  int nn = N >> 7;
  int ntiles = ((rows + 127) >> 7) * nn;
  const u16* B = Bt + (long)e * strideB;
  const float* bvec = bias + (long)e * strideBias;
  __shared__ __align__(16) u16 lA[2][128 * 64];
  __shared__ __align__(16) u16 lB[2][128 * 64];
  int tid = threadIdx.x, lane = tid & 63, w = tid >> 6;
  int wr = w >> 1, wc = w & 1;
  int l15 = lane & 15, l4 = lane >> 4;
  int lr8 = lane >> 3;                         // 0..7: row within 8-row group
  int csrc = ((lane & 7) ^ lr8) * 8;           // inverse-swizzled src chunk (shorts)
  int nt = K >> 6;

  for (int t = slot; t < ntiles; t += 256) {
    int rbk = t / nn, nb = t - rbk * nn;
    int m0 = r0 + rbk * 128;
    long n0 = (long)nb * 128;
    u32 asrc[4], bsrc[4];
#pragma unroll
    for (int r = 0; r < 4; r++) {
      int row = w * 32 + r * 8 + lr8;
      int g = m0 + row; if (g > r1 - 1) g = r1 - 1;
      int ar = (EPI == 2) ? tlist[g] : g;
      asrc[r] = (u32)ar * (u32)K + csrc;
      bsrc[r] = (u32)(n0 + row) * (u32)K + csrc;
    }
    f32x4 acc[4][4];
    f32x4 zz = {0.0f, 0.0f, 0.0f, 0.0f};
#pragma unroll
    for (int i = 0; i < 4; i++)
#pragma unroll
      for (int j = 0; j < 4; j++) acc[i][j] = zz;

#define STAGE_MOE(buf, k0_) do { u32 o_ = (k0_); \
    _Pragma("unroll") \
    for (int r = 0; r < 4; r++) { \
      gload16(&A[asrc[r] + o_], &lA[buf][(w * 32 + r * 8) * 64]); \
      gload16(&B[bsrc[r] + o_], &lB[buf][(w * 32 + r * 8) * 64]); \
    } } while (0)

    STAGE_MOE(0, 0);
    __syncthreads();
    int cur = 0;
    for (int s = 0; s < nt; s++) {
      if (s + 1 < nt) STAGE_MOE(cur ^ 1, (u32)(s + 1) * 64);
#pragma unroll
      for (int ks = 0; ks < 2; ks++) {
        bf16x8 af[4], bq[4];
#pragma unroll
        for (int mi = 0; mi < 4; mi++) {
          int row = wr * 64 + mi * 16 + l15;
          af[mi] = *(const bf16x8*)&lA[cur][row * 64 + (((ks * 4 + l4) ^ (l15 & 7)) * 8)];
        }
#pragma unroll
        for (int ni = 0; ni < 4; ni++) {
          int row = wc * 64 + ni * 16 + l15;
          bq[ni] = *(const bf16x8*)&lB[cur][row * 64 + (((ks * 4 + l4) ^ (l15 & 7)) * 8)];
        }
#pragma unroll
        for (int mi = 0; mi < 4; mi++)
#pragma unroll
          for (int ni = 0; ni < 4; ni++)
            acc[mi][ni] = __builtin_amdgcn_mfma_f32_16x16x32_bf16(af[mi], bq[ni], acc[mi][ni], 0, 0, 0);
      }
      __syncthreads();
      cur ^= 1;
    }
#undef STAGE_MOE
#pragma unroll
    for (int mi = 0; mi < 4; mi++) {
#pragma unroll
      for (int j = 0; j < 4; j++) {
        int row = m0 + wr * 64 + mi * 16 + l4 * 4 + j;
        if (row < r1) {
#pragma unroll
          for (int ni = 0; ni < 4; ni++) {
            long col = n0 + wc * 64 + ni * 16 + l15;
            float vv = acc[mi][ni][j] + bvec[col];
            if (EPI == 2) {
              ((u16*)Cout)[(long)row * N + col] = f2b(gelu_exact(vv));
            } else {
              ((float*)Cout)[(long)row * N + col] = vv;
            }
          }
        }
      }
    }
  }
}

// ---------------- combine: out = x1 + w0*oute[s0] + w1*oute[s1] -----------
__global__ __launch_bounds__(256) void k_combine(
    const float* __restrict__ x1, const float* __restrict__ oute,
    const int* __restrict__ slot_of, const float* __restrict__ wts,
    float* __restrict__ out)
{
  int t = blockIdx.x;
  int c = threadIdx.x * 4;
  int s0 = slot_of[2 * t], s1 = slot_of[2 * t + 1];
  float w0 = wts[2 * t], w1 = wts[2 * t + 1];
  float4 a  = *(const float4*)&x1[(long)t * 1024 + c];
  float4 e0 = *(const float4*)&oute[(long)s0 * 1024 + c];
  float4 e1 = *(const float4*)&oute[(long)s1 * 1024 + c];
  float4 r;
  r.x = a.x + w0 * e0.x + w1 * e1.x;
  r.y = a.y + w0 * e0.y + w1 * e1.y;
  r.z = a.z + w0 * e0.z + w1 * e1.z;
  r.w = a.w + w0 * e0.w + w1 * e1.w;
  *(float4*)&out[(long)t * 1024 + c] = r;
}

// ===========================================================================
extern "C" void kernel_launch(void* const* d_in, const int* in_sizes, int n_in,
                              void* d_out, int out_size, void* d_ws, size_t ws_size,
                              hipStream_t stream)
{
  const float* x    = (const float*)d_in[0];
  const float* ln1s = (const float*)d_in[2];
  const float* ln1b = (const float*)d_in[3];
  const float* Wq   = (const float*)d_in[4];
  const float* Wdkv = (const float*)d_in[5];
  const float* Wukv = (const float*)d_in[6];
  const float* Wo   = (const float*)d_in[7];
  const float* ln2s = (const float*)d_in[8];
  const float* ln2b = (const float*)d_in[9];
  const float* Wg   = (const float*)d_in[10];
  const float* bg   = (const float*)d_in[11];
  const float* We1  = (const float*)d_in[12];
  const float* be1  = (const float*)d_in[13];
  const float* We2  = (const float*)d_in[14];
  const float* be2  = (const float*)d_in[15];
  float* out = (float*)d_out;

  char* wp = (char*)d_ws;
  auto take = [&](size_t nbytes) -> void* {
    char* r = wp; wp += (nbytes + 255) & ~(size_t)255; return (void*)r;
  };
  u16* We1t = (u16*)take(8L * 2048 * 1024 * 2);
  u16* We2t = (u16*)take(8L * 1024 * 2048 * 2);
  u16* hh   = (u16*)take(4096L * 1024 * 2);
  u16* hl   = (u16*)take(4096L * 1024 * 2);
  u16* qh   = (u16*)take(4096L * 1024 * 2);
  u16* ql   = (u16*)take(4096L * 1024 * 2);
  u16* kvh  = (u16*)take(4096L * 1024 * 2);
  u16* kvl  = (u16*)take(4096L * 1024 * 2);
  u16* kvTh = (u16*)take(4096L * 1024 * 2);
  u16* kvTl = (u16*)take(4096L * 1024 * 2);
  u16* cbh  = (u16*)take(4096L * 512 * 2);
  u16* cbl  = (u16*)take(4096L * 512 * 2);
  float* x1 = (float*)take(4096L * 1024 * 4);
  u16* hid  = (u16*)take(8192L * 2048 * 2);
  int*   sel   = (int*)take(8192 * 4);
  float* wts   = (float*)take(8192 * 4);
  int*   cnt   = (int*)take(64);
  int*   offs  = (int*)take(64);
  int*   tlist = (int*)take(8192 * 4);
  int*   slot  = (int*)take(8192 * 4);
  // phase-based aliases (lifetimes disjoint on the in-order stream):
  u16* attn_h = hh;                 // hh/hl dead after Wq+Wdkv GEMMs
  u16* attn_l = hl;
  u16* h2bf   = cbh;                // spans cbh+cbl (dead after kv-up GEMM)
  float* oute = (float*)qh;         // spans qh+ql (dead after flash)
  float* Pk   = (float*)We2t;       // split-K partials (32 MB); We2 transposed AFTER
  // split attention weights live in `hid` (dead until k_gemm_moe<2>): 12 MB
  u16* Wqh   = hid;
  u16* Wql   = Wqh   + 1024L * 1024;
  u16* Wdkvh = Wql   + 1024L * 1024;
  u16* Wdkvl = Wdkvh + 512L * 1024;
  u16* Wukvh = Wdkvl + 512L * 1024;
  u16* Wukvl = Wukvh + 1024L * 512;
  u16* Woh   = Wukvl + 1024L * 512;
  u16* Wol   = Woh   + 1024L * 1024;
  if ((size_t)(wp - (char*)d_ws) > ws_size) return;

  dim3 b256(256);
  // attention weights -> split hi/lo bf16, K-major
  k_split_transpose<<<dim3(16, 16), b256, 0, stream>>>(Wq,   Wqh,   Wql,   1024, 1024);
  k_split_transpose<<<dim3(8, 16),  b256, 0, stream>>>(Wdkv, Wdkvh, Wdkvl, 1024, 512);
  k_split_transpose<<<dim3(16, 8),  b256, 0, stream>>>(Wukv, Wukvh, Wukvl, 512, 1024);
  k_split_transpose<<<dim3(16, 16), b256, 0, stream>>>(Wo,   Woh,   Wol,   1024, 1024);
  // attention path (split-bf16 MFMA + split-K2, fp32-equivalent accuracy)
  k_layernorm<2><<<dim3(4096), b256, 0, stream>>>(x, ln1s, ln1b, hh, hl);
  k_gemm_bf3<<<dim3(512), b256, 0, stream>>>(hh, hl, Wqh, Wql, Pk, 4096, 1024, 1024);
  k_red_split<<<dim3(4096), b256, 0, stream>>>(Pk, qh, ql, 4096L * 1024);
  k_gemm_bf3<<<dim3(256), b256, 0, stream>>>(hh, hl, Wdkvh, Wdkvl, Pk, 4096, 512, 1024);
  k_red_split<<<dim3(2048), b256, 0, stream>>>(Pk, cbh, cbl, 4096L * 512);
  k_gemm_bf3<<<dim3(512), b256, 0, stream>>>(cbh, cbl, Wukvh, Wukvl, Pk, 4096, 1024, 512);
  k_red_kv<<<dim3(32, 32), b256, 0, stream>>>(Pk, kvh, kvl, kvTh, kvTl);
  k_flash_v3<<<dim3(32, 32), b256, 0, stream>>>(qh, ql, kvh, kvl, kvTh, kvTl, attn_h, attn_l);
  k_gemm_bf3<<<dim3(512), b256, 0, stream>>>(attn_h, attn_l, Woh, Wol, Pk, 4096, 1024, 1024);
  k_red_resid<<<dim3(4096), b256, 0, stream>>>(Pk, x, x1, 4096L * 1024);
  // MoE
  k_layernorm<1><<<dim3(4096), b256, 0, stream>>>(x1, ln2s, ln2b, h2bf, nullptr);
  k_gate<<<dim3(1024), b256, 0, stream>>>(x1, ln2s, ln2b, Wg, bg, sel, wts);
  k_count<<<dim3(8), b256, 0, stream>>>(sel, cnt);
  k_offsets<<<dim3(1), dim3(64), 0, stream>>>(cnt, offs);
  k_scatter<<<dim3(8), b256, 0, stream>>>(sel, offs, tlist, slot);
  // expert weights -> bf16, K-major (after Pk is dead: Pk aliases We2t)
  k_transpose_bf16<<<dim3(32, 16, 8), b256, 0, stream>>>(We1, We1t, 1024, 2048);
  k_transpose_bf16<<<dim3(16, 32, 8), b256, 0, stream>>>(We2, We2t, 2048, 1024);
  k_gemm_moe<2><<<dim3(2048), b256, 0, stream>>>(h2bf, We1t, hid, be1, tlist, offs,
                                                 2048, 1024, 2048L * 1024, 2048);
  k_gemm_moe<3><<<dim3(2048), b256, 0, stream>>>(hid, We2t, oute, be2, tlist, offs,
                                                 1024, 2048, 1024L * 2048, 1024);
  k_combine<<<dim3(4096), b256, 0, stream>>>(x1, oute, slot, wts, out);
}

// Round 15
// 474.883 us; speedup vs baseline: 1.0775x; 1.0358x over previous
//
#include <hip/hip_runtime.h>

#define EPS_LN 1e-5f

typedef __attribute__((ext_vector_type(4))) float f32x4;
typedef __attribute__((ext_vector_type(8))) __bf16 bf16x8;
typedef __attribute__((ext_vector_type(2))) unsigned int u32x2;
typedef unsigned int u32;
typedef unsigned short u16;

__device__ __forceinline__ u16 f2b(float f) {
  unsigned int u = __builtin_bit_cast(unsigned int, f);
  unsigned int r = (u + 0x7FFFu + ((u >> 16) & 1u)) >> 16;
  return (u16)r;
}
__device__ __forceinline__ float b2f(u16 s) {
  unsigned int u = ((unsigned int)s) << 16;
  return __builtin_bit_cast(float, u);
}
__device__ __forceinline__ void splitf(float v, u16& h, u16& l) {
  h = f2b(v); l = f2b(v - b2f(h));
}
__device__ __forceinline__ float gelu_exact(float v) {
  return 0.5f * v * (1.0f + erff(v * 0.70710678118654752440f));
}
// async global->LDS, 16B/lane; LDS dest = wave-uniform base + lane*16
__device__ __forceinline__ void gload16(const void* g, void* l) {
  __builtin_amdgcn_global_load_lds((const __attribute__((address_space(1))) u32*)g,
                                   (__attribute__((address_space(3))) u32*)l, 16, 0, 0);
}
// PV matrix step: D += A*B via v_mfma_f32_16x16x16_bf16 (inline asm).
__device__ __forceinline__ void pv_mfma(f32x4& o, u32x2 a, u32x2 b) {
  asm("s_nop 1\n\tv_mfma_f32_16x16x16_bf16 %0, %1, %2, %0" : "+v"(o) : "v"(a), "v"(b));
}
// flash LDS tile accessor: 64 rows x 64 shorts, XOR-swizzled 16B chunks
__device__ __forceinline__ int fsw(int row, int sc) {
  return row * 64 + ((((sc >> 3) ^ (row & 7))) << 3) + (sc & 7);
}

// ---------------- transpose fp32 [K][N] -> bf16 [N][K] (batched over z) ----
__global__ __launch_bounds__(256) void k_transpose_bf16(
    const float* __restrict__ src, u16* __restrict__ dst, int K, int N)
{
  __shared__ u16 t[64][65];
  long base = (long)blockIdx.z * (long)K * (long)N;
  const float* s = src + base;
  u16* d = dst + base;
  int n0 = blockIdx.x * 64, k0 = blockIdx.y * 64;
  int c = threadIdx.x & 63, r = threadIdx.x >> 6;
#pragma unroll
  for (int i = 0; i < 16; i++) {
    int k = r * 16 + i;
    t[c][k] = f2b(s[(long)(k0 + k) * N + n0 + c]);
  }
  __syncthreads();
#pragma unroll
  for (int i = 0; i < 16; i++) {
    int n = r * 16 + i;
    d[(long)(n0 + n) * K + k0 + c] = t[n][c];
  }
}

// ------------- split-transpose fp32 [K][N] -> bf16 hi/lo [N][K] ------------
__global__ __launch_bounds__(256) void k_split_transpose(
    const float* __restrict__ src, u16* __restrict__ dh,
    u16* __restrict__ dl, int K, int N)
{
  __shared__ float t[64][65];
  int n0 = blockIdx.x * 64, k0 = blockIdx.y * 64;
  int c = threadIdx.x & 63, r4 = threadIdx.x >> 6;
#pragma unroll
  for (int i = 0; i < 16; i++) {
    int k = r4 * 16 + i;
    t[c][k] = src[(long)(k0 + k) * N + n0 + c];
  }
  __syncthreads();
#pragma unroll
  for (int i = 0; i < 16; i++) {
    int n = r4 * 16 + i;
    float v = t[n][c];
    u16 h = f2b(v);
    dh[(long)(n0 + n) * K + k0 + c] = h;
    dl[(long)(n0 + n) * K + k0 + c] = f2b(v - b2f(h));
  }
}

// --- fused kv: sum split-K partials -> split hi/lo -> natural + transposed -
__global__ __launch_bounds__(256) void k_red_kv(
    const float* __restrict__ P, u16* __restrict__ kvh, u16* __restrict__ kvl,
    u16* __restrict__ kvTh, u16* __restrict__ kvTl)
{
  __shared__ u16 th[64][65];
  __shared__ u16 tl[64][65];
  const long MN = 4096L * 1024;
  int bh = blockIdx.y, s0 = blockIdx.x * 64;
  int b = bh >> 4, h = bh & 15;
  int c = threadIdx.x & 63, r = threadIdx.x >> 6;
  long ibase = ((long)b * 2048 + s0) * 1024 + h * 64;
  long obase = (long)bh * 64 * 2048 + s0;
#pragma unroll
  for (int i = 0; i < 16; i++) {
    int k = r * 16 + i;
    long idx = ibase + (long)k * 1024 + c;
    float v = P[idx] + P[MN + idx];
    u16 hh_, ll_; splitf(v, hh_, ll_);
    kvh[idx] = hh_; kvl[idx] = ll_;
    th[c][k] = hh_; tl[c][k] = ll_;
  }
  __syncthreads();
#pragma unroll
  for (int i = 0; i < 16; i++) {
    int n = r * 16 + i;
    kvTh[obase + (long)n * 2048 + c] = th[n][c];
    kvTl[obase + (long)n * 2048 + c] = tl[n][c];
  }
}

// ---------------- LayerNorm: MODE 1 = single bf16, MODE 2 = split hi/lo ----
template<int MODE>
__global__ __launch_bounds__(256) void k_layernorm(
    const float* __restrict__ x, const float* __restrict__ g,
    const float* __restrict__ b, u16* __restrict__ o1, u16* __restrict__ o2)
{
  int row = blockIdx.x, tid = threadIdx.x;
  const float* xr = x + (long)row * 1024;
  float4 v = *(const float4*)&xr[tid * 4];
  float s = v.x + v.y + v.z + v.w;
  float sq = v.x * v.x + v.y * v.y + v.z * v.z + v.w * v.w;
#pragma unroll
  for (int o = 32; o; o >>= 1) { s += __shfl_down(s, o); sq += __shfl_down(sq, o); }
  __shared__ float red[8];
  int wave = tid >> 6, lane = tid & 63;
  if (lane == 0) { red[wave] = s; red[4 + wave] = sq; }
  __syncthreads();
  s  = red[0] + red[1] + red[2] + red[3];
  sq = red[4] + red[5] + red[6] + red[7];
  float mean = s * (1.0f / 1024.0f);
  float var  = sq * (1.0f / 1024.0f) - mean * mean;
  float rs = rsqrtf(var + EPS_LN);
  float4 gg = *(const float4*)&g[tid * 4];
  float4 bb = *(const float4*)&b[tid * 4];
  float ov[4];
  ov[0] = (v.x - mean) * rs * gg.x + bb.x;
  ov[1] = (v.y - mean) * rs * gg.y + bb.y;
  ov[2] = (v.z - mean) * rs * gg.z + bb.z;
  ov[3] = (v.w - mean) * rs * gg.w + bb.w;
  if (MODE == 1) {
    ushort4 o4; o4.x = f2b(ov[0]); o4.y = f2b(ov[1]); o4.z = f2b(ov[2]); o4.w = f2b(ov[3]);
    *(ushort4*)&o1[(long)row * 1024 + tid * 4] = o4;
  } else {
    ushort4 hh, ll;
    splitf(ov[0], hh.x, ll.x); splitf(ov[1], hh.y, ll.y);
    splitf(ov[2], hh.z, ll.z); splitf(ov[3], hh.w, ll.w);
    *(ushort4*)&o1[(long)row * 1024 + tid * 4] = hh;
    *(ushort4*)&o2[(long)row * 1024 + tid * 4] = ll;
  }
}

// ------- split-bf16 3-term MFMA GEMM v2, SPLIT-K x2, swizzled LDS ----------
__global__ __launch_bounds__(256) void k_gemm_bf3(
    const u16* __restrict__ Ah, const u16* __restrict__ Al,
    const u16* __restrict__ Bh, const u16* __restrict__ Bl,
    float* __restrict__ P, int M, int N, int K)
{
  int split = blockIdx.x & 1;
  int bid = blockIdx.x >> 1;
  int nwg = gridDim.x >> 1, cpx = nwg >> 3;
  int wg = (bid & 7) * cpx + (bid >> 3);       // XCD-chunked
  int mm = M >> 7;
  int mb = wg % mm, nb = wg / mm;              // m-fast: B panel pinned per XCD
  long m0 = (long)mb * 128, n0 = (long)nb * 128;
  int K2 = K >> 1;
  int kbase = split * K2;
  __shared__ __align__(16) u16 sA[2][128 * 64];
  __shared__ __align__(16) u16 sB[2][128 * 64];
  int tid = threadIdx.x, lane = tid & 63, w = tid >> 6;
  int wr = w >> 1, wc = w & 1, l15 = lane & 15, l4 = lane >> 4;
  int lr8 = lane >> 3;                         // row within 8-row stripe
  int cl = (lane & 7) ^ lr8;                   // logical chunk this lane stages
  int scol = (cl & 3) * 8;                     // k-chunk col within the half
  const u16* bA = (cl < 4) ? Ah : Al;          // hi or lo source array
  const u16* bB = (cl < 4) ? Bh : Bl;
  long a_off[4], b_off[4];
#pragma unroll
  for (int r = 0; r < 4; r++) {
    int row = w * 32 + r * 8 + lr8;
    a_off[r] = (m0 + row) * (long)K + kbase + scol;
    b_off[r] = (n0 + row) * (long)K + kbase + scol;
  }
  int nt = K2 >> 5;

  f32x4 acc[4][4];
  f32x4 zz = {0.0f, 0.0f, 0.0f, 0.0f};
#pragma unroll
  for (int i = 0; i < 4; i++)
#pragma unroll
    for (int j = 0; j < 4; j++) acc[i][j] = zz;

#define STAGE_BF3(buf, s_) do { long o = (long)(s_) * 32; \
    _Pragma("unroll") \
    for (int r = 0; r < 4; r++) { \
      gload16(&bA[a_off[r] + o], &sA[buf][(w * 32 + r * 8) * 64]); \
      gload16(&bB[b_off[r] + o], &sB[buf][(w * 32 + r * 8) * 64]); \
    } } while (0)

  STAGE_BF3(0, 0);
  __syncthreads();
  int cur = 0;
  for (int s = 0; s < nt; s++) {
    if (s + 1 < nt) STAGE_BF3(cur ^ 1, s + 1);
    bf16x8 ah[4], al[4], bh[4], bl[4];
#pragma unroll
    for (int mi = 0; mi < 4; mi++) {
      int row = wr * 64 + mi * 16 + l15;
      int k7 = l15 & 7;
      ah[mi] = *(const bf16x8*)&sA[cur][row * 64 + ((l4 ^ k7) * 8)];
      al[mi] = *(const bf16x8*)&sA[cur][row * 64 + (((4 + l4) ^ k7) * 8)];
    }
#pragma unroll
    for (int ni = 0; ni < 4; ni++) {
      int row = wc * 64 + ni * 16 + l15;
      int k7 = l15 & 7;
      bh[ni] = *(const bf16x8*)&sB[cur][row * 64 + ((l4 ^ k7) * 8)];
      bl[ni] = *(const bf16x8*)&sB[cur][row * 64 + (((4 + l4) ^ k7) * 8)];
    }
#pragma unroll
    for (int mi = 0; mi < 4; mi++)
#pragma unroll
      for (int ni = 0; ni < 4; ni++) {
        acc[mi][ni] = __builtin_amdgcn_mfma_f32_16x16x32_bf16(ah[mi], bh[ni], acc[mi][ni], 0, 0, 0);
        acc[mi][ni] = __builtin_amdgcn_mfma_f32_16x16x32_bf16(ah[mi], bl[ni], acc[mi][ni], 0, 0, 0);
        acc[mi][ni] = __builtin_amdgcn_mfma_f32_16x16x32_bf16(al[mi], bh[ni], acc[mi][ni], 0, 0, 0);
      }
    __syncthreads();
    cur ^= 1;
  }
#undef STAGE_BF3
  long base = (long)split * M * N;
#pragma unroll
  for (int mi = 0; mi < 4; mi++) {
#pragma unroll
    for (int j = 0; j < 4; j++) {
      long row = m0 + wr * 64 + mi * 16 + l4 * 4 + j;
#pragma unroll
      for (int ni = 0; ni < 4; ni++) {
        long col = n0 + wc * 64 + ni * 16 + l15;
        P[base + row * N + col] = acc[mi][ni][j];
      }
    }
  }
}

// ---- split-K reduces: out = p0 + p1 (+aux), split-bf16 or fp32 ------------
__global__ __launch_bounds__(256) void k_red_split(
    const float* __restrict__ P, u16* __restrict__ Ch, u16* __restrict__ Cl, long MN)
{
  long i = ((long)blockIdx.x * 256 + threadIdx.x) * 4;
  float4 a = *(const float4*)&P[i];
  float4 b = *(const float4*)&P[MN + i];
  ushort4 h, l;
  splitf(a.x + b.x, h.x, l.x); splitf(a.y + b.y, h.y, l.y);
  splitf(a.z + b.z, h.z, l.z); splitf(a.w + b.w, h.w, l.w);
  *(ushort4*)&Ch[i] = h;
  *(ushort4*)&Cl[i] = l;
}

__global__ __launch_bounds__(256) void k_red_resid(
    const float* __restrict__ P, const float* __restrict__ x,
    float* __restrict__ out, long MN)
{
  long i = ((long)blockIdx.x * 256 + threadIdx.x) * 4;
  float4 a = *(const float4*)&P[i];
  float4 b = *(const float4*)&P[MN + i];
  float4 xv = *(const float4*)&x[i];
  float4 r = {a.x + b.x + xv.x, a.y + b.y + xv.y, a.z + b.z + xv.z, a.w + b.w + xv.w};
  *(float4*)&out[i] = r;
}

// ------------- split-bf16 MFMA causal flash attention (v3) ----------------
__global__ __launch_bounds__(256) void k_flash_v3(
    const u16* __restrict__ Qh, const u16* __restrict__ Ql,
    const u16* __restrict__ Kh, const u16* __restrict__ Kl,
    const u16* __restrict__ Th, const u16* __restrict__ Tl,
    u16* __restrict__ Oh, u16* __restrict__ Ol)
{
  int qb = (int)gridDim.y - 1 - (int)blockIdx.y;  // heavy tiles first
  int bh = blockIdx.x;
  int q0 = qb * 64;
  int tid = threadIdx.x, lane = tid & 63, w = tid >> 6;
  int l15 = lane & 15, l4 = lane >> 4;
  __shared__ __align__(16) u16 Qsh[4096], Qsl[4096];
  __shared__ __align__(16) u16 Ksh[2][4096], Ksl[2][4096];
  __shared__ __align__(16) u16 Tsh[2][4096], Tsl[2][4096];
  long rowb = (long)(bh >> 4) * 2048;          // token row base
  int  colo = (bh & 15) * 64;                  // head col offset
  long tbase = (long)bh * 64 * 2048;           // kvT base
  int r8 = lane >> 3;
  int c8s = ((lane & 7) ^ r8) * 8;             // swizzled source chunk (shorts)

#pragma unroll
  for (int k = 0; k < 2; k++) {
    int rr = w * 16 + k * 8;
    long src = (rowb + q0 + rr + r8) * 1024 + colo + c8s;
    gload16(&Qh[src], &Qsh[rr * 64]);
    gload16(&Ql[src], &Qsl[rr * 64]);
  }
#pragma unroll
  for (int k = 0; k < 2; k++) {
    int rr = w * 16 + k * 8;
    long srcK = (rowb + rr + r8) * 1024 + colo + c8s;
    long srcT = tbase + (long)(rr + r8) * 2048 + c8s;
    gload16(&Kh[srcK], &Ksh[0][rr * 64]);
    gload16(&Kl[srcK], &Ksl[0][rr * 64]);
    gload16(&Th[srcT], &Tsh[0][rr * 64]);
    gload16(&Tl[srcT], &Tsl[0][rr * 64]);
  }
  __syncthreads();

  float m = -1e30f, lsum = 0.0f;
  f32x4 o[4];
  f32x4 zz = {0.0f, 0.0f, 0.0f, 0.0f};
#pragma unroll
  for (int nb = 0; nb < 4; nb++) o[nb] = zz;
  int cur = 0;

  for (int kt = 0; kt <= qb; kt++) {
    int k0 = kt * 64;
    if (kt < qb) {
      int kn = k0 + 64, nxt = cur ^ 1;
#pragma unroll
      for (int k = 0; k < 2; k++) {
        int rr = w * 16 + k * 8;
        long srcK = (rowb + kn + rr + r8) * 1024 + colo + c8s;
        long srcT = tbase + (long)(rr + r8) * 2048 + kn + c8s;
        gload16(&Kh[srcK], &Ksh[nxt][rr * 64]);
        gload16(&Kl[srcK], &Ksl[nxt][rr * 64]);
        gload16(&Th[srcT], &Tsh[nxt][rr * 64]);
        gload16(&Tl[srcT], &Tsl[nxt][rr * 64]);
      }
    }
    f32x4 sT[4];
#pragma unroll
    for (int mi = 0; mi < 4; mi++) sT[mi] = zz;
#pragma unroll
    for (int ds = 0; ds < 2; ds++) {
      int qoff = fsw(w * 16 + l15, ds * 32 + l4 * 8);
      bf16x8 qh = *(const bf16x8*)&Qsh[qoff];
      bf16x8 ql = *(const bf16x8*)&Qsl[qoff];
#pragma unroll
      for (int mi = 0; mi < 4; mi++) {
        int koff = fsw(mi * 16 + l15, ds * 32 + l4 * 8);
        bf16x8 kh = *(const bf16x8*)&Ksh[cur][koff];
        bf16x8 kl = *(const bf16x8*)&Ksl[cur][koff];
        sT[mi] = __builtin_amdgcn_mfma_f32_16x16x32_bf16(kh, qh, sT[mi], 0, 0, 0);
        sT[mi] = __builtin_amdgcn_mfma_f32_16x16x32_bf16(kh, ql, sT[mi], 0, 0, 0);
        sT[mi] = __builtin_amdgcn_mfma_f32_16x16x32_bf16(kl, qh, sT[mi], 0, 0, 0);
      }
    }
    bool diag = (kt == qb);
    int qg = q0 + w * 16 + l15;
    float p[4][4];
    float tm = -1e30f;
#pragma unroll
    for (int mi = 0; mi < 4; mi++)
#pragma unroll
      for (int r = 0; r < 4; r++) {
        float v = sT[mi][r] * 0.125f;
        if (diag && (k0 + mi * 16 + l4 * 4 + r > qg)) v = -1e30f;
        p[mi][r] = v; tm = fmaxf(tm, v);
      }
    tm = fmaxf(tm, __shfl_xor(tm, 16));
    tm = fmaxf(tm, __shfl_xor(tm, 32));
    float mn = fmaxf(m, tm);
    float corr = __expf(m - mn);
    m = mn;
    float rs = 0.0f;
#pragma unroll
    for (int mi = 0; mi < 4; mi++)
#pragma unroll
      for (int r = 0; r < 4; r++) {
        float pv = __expf(p[mi][r] - mn);
        p[mi][r] = pv; rs += pv;
      }
    rs += __shfl_xor(rs, 16);
    rs += __shfl_xor(rs, 32);
    lsum = lsum * corr + rs;
    float corrO[4];
#pragma unroll
    for (int r = 0; r < 4; r++) corrO[r] = __shfl(corr, l4 * 4 + r);
#pragma unroll
    for (int nb = 0; nb < 4; nb++)
#pragma unroll
      for (int r = 0; r < 4; r++) o[nb][r] *= corrO[r];
    u32x2 pah[4], pal[4];
#pragma unroll
    for (int mi = 0; mi < 4; mi++) {
      u16 h[4], l[4];
#pragma unroll
      for (int r = 0; r < 4; r++) splitf(p[mi][r], h[r], l[r]);
      pah[mi][0] = (u32)h[0] | ((u32)h[1] << 16);
      pah[mi][1] = (u32)h[2] | ((u32)h[3] << 16);
      pal[mi][0] = (u32)l[0] | ((u32)l[1] << 16);
      pal[mi][1] = (u32)l[2] | ((u32)l[3] << 16);
    }
#pragma unroll
    for (int nb = 0; nb < 4; nb++) {
#pragma unroll
      for (int mi = 0; mi < 4; mi++) {
        int toff = fsw(nb * 16 + l15, mi * 16 + l4 * 4);
        u32x2 vh = *(const u32x2*)&Tsh[cur][toff];
        u32x2 vl = *(const u32x2*)&Tsl[cur][toff];
        pv_mfma(o[nb], pah[mi], vh);
        pv_mfma(o[nb], pah[mi], vl);
        pv_mfma(o[nb], pal[mi], vh);
      }
    }
    __syncthreads();
    cur ^= 1;
  }
  __builtin_amdgcn_sched_barrier(0);
  asm volatile("s_nop 7\n\ts_nop 7" ::: "memory");
  __builtin_amdgcn_sched_barrier(0);
  float inv[4];
#pragma unroll
  for (int r = 0; r < 4; r++) inv[r] = 1.0f / __shfl(lsum, l4 * 4 + r);
#pragma unroll
  for (int nb = 0; nb < 4; nb++)
#pragma unroll
    for (int r = 0; r < 4; r++) {
      long idx = (rowb + q0 + w * 16 + l4 * 4 + r) * 1024 + colo + nb * 16 + l15;
      u16 hh_, ll_; splitf(o[nb][r] * inv[r], hh_, ll_);
      Oh[idx] = hh_; Ol[idx] = ll_;
    }
}

// ---------------- gate: fp32 inline-LN + logits + top2 --------------------
__global__ __launch_bounds__(256) void k_gate(
    const float* __restrict__ x1, const float* __restrict__ g2, const float* __restrict__ b2,
    const float* __restrict__ Wg, const float* __restrict__ bg,
    int* __restrict__ sel, float* __restrict__ wts)
{
  int t = blockIdx.x * 4 + (threadIdx.x >> 6);
  int lane = threadIdx.x & 63;
  const float* xr = x1 + (long)t * 1024;
  float v[16], s = 0.0f, sq = 0.0f;
#pragma unroll
  for (int i = 0; i < 16; i++) { v[i] = xr[lane + 64 * i]; s += v[i]; sq += v[i] * v[i]; }
#pragma unroll
  for (int o = 32; o; o >>= 1) { s += __shfl_xor(s, o); sq += __shfl_xor(sq, o); }
  float mean = s * (1.0f / 1024.0f);
  float var = sq * (1.0f / 1024.0f) - mean * mean;
  float rs = rsqrtf(var + EPS_LN);
  float acc[8];
#pragma unroll
  for (int e = 0; e < 8; e++) acc[e] = 0.0f;
#pragma unroll
  for (int i = 0; i < 16; i++) {
    int d = lane + 64 * i;
    float hh = (v[i] - mean) * rs * g2[d] + b2[d];
    float4 w0 = *(const float4*)&Wg[d * 8];
    float4 w1 = *(const float4*)&Wg[d * 8 + 4];
    acc[0] += hh * w0.x; acc[1] += hh * w0.y; acc[2] += hh * w0.z; acc[3] += hh * w0.w;
    acc[4] += hh * w1.x; acc[5] += hh * w1.y; acc[6] += hh * w1.z; acc[7] += hh * w1.w;
  }
#pragma unroll
  for (int o = 32; o; o >>= 1)
#pragma unroll
    for (int e = 0; e < 8; e++) acc[e] += __shfl_xor(acc[e], o);
  if (lane == 0) {
    float le[8];
#pragma unroll
    for (int e = 0; e < 8; e++) le[e] = acc[e] + bg[e];
    int i0 = 0;
    for (int e = 1; e < 8; e++) if (le[e] > le[i0]) i0 = e;
    int i1 = (i0 == 0) ? 1 : 0;
    for (int e = 0; e < 8; e++) if (e != i0 && le[e] > le[i1]) i1 = e;
    float w0 = 1.0f / (1.0f + __expf(le[i1] - le[i0]));
    sel[2 * t] = i0; sel[2 * t + 1] = i1;
    wts[2 * t] = w0; wts[2 * t + 1] = 1.0f - w0;
  }
}

// ---------------- routing: count / offsets / deterministic scatter --------
__global__ __launch_bounds__(256) void k_count(const int* __restrict__ sel, int* __restrict__ cnt)
{
  int e = blockIdx.x, tid = threadIdx.x;
  int c = 0;
  for (int t = tid; t < 4096; t += 256)
    c += (sel[2 * t] == e) + (sel[2 * t + 1] == e);
#pragma unroll
  for (int o = 32; o; o >>= 1) c += __shfl_down(c, o);
  __shared__ int red[4];
  int wave = tid >> 6, lane = tid & 63;
  if (lane == 0) red[wave] = c;
  __syncthreads();
  if (tid == 0) cnt[e] = red[0] + red[1] + red[2] + red[3];
}

__global__ void k_offsets(const int* __restrict__ cnt, int* __restrict__ offs)
{
  if (threadIdx.x == 0) {
    int a = 0; offs[0] = 0;
    for (int e = 0; e < 8; e++) { a += cnt[e]; offs[e + 1] = a; }
  }
}

__global__ __launch_bounds__(256) void k_scatter(
    const int* __restrict__ sel, const int* __restrict__ offs,
    int* __restrict__ tlist, int* __restrict__ slot_of)
{
  int e = blockIdx.x, tid = threadIdx.x;
  int lane = tid & 63, wave = tid >> 6;
  __shared__ int wsum[4];
  int base = offs[e];
  for (int t0 = 0; t0 < 4096; t0 += 256) {
    int t = t0 + tid;
    int s0 = sel[2 * t], s1 = sel[2 * t + 1];
    bool p = (s0 == e) || (s1 == e);
    int k = (s0 == e) ? 0 : 1;
    unsigned long long mb = __ballot(p);
    int rank = __popcll(mb & ((1ull << lane) - 1ull));
    if (lane == 0) wsum[wave] = __popcll(mb);
    __syncthreads();
    int wbase = 0;
    for (int w = 0; w < wave; w++) wbase += wsum[w];
    if (p) { int idx = base + wbase + rank; tlist[idx] = t; slot_of[2 * t + k] = idx; }
    base += wsum[0] + wsum[1] + wsum[2] + wsum[3];
    __syncthreads();
  }
}

// ------- grouped bf16 MFMA GEMM v8: r7 K-loop, 8 waves/block (512 thr) ----
// Same tile (128x128), BK=64, swizzle, mapping as proven r7/r12. 8 waves as
// 2M x 4N (wave tile 64x32, acc[4][2]) -> 2 blocks/CU = 16 waves/CU = 4/SIMD
// (vs 2/SIMD at 256 thr): more resident waves to hide the barrier drain.
template<int EPI>
__global__ __launch_bounds__(512, 1) void k_gemm_moe(
    const u16* __restrict__ A, const u16* __restrict__ Bt,
    void* __restrict__ Cout, const float* __restrict__ bias,
    const int* __restrict__ tlist, const int* __restrict__ offs,
    int N, int K, long strideB, int strideBias)
{
  int e = blockIdx.x & 7, slot = blockIdx.x >> 3;
  int r0 = offs[e], r1 = offs[e + 1];
  int rows = r1 - r0;
  if (rows <= 0) return;
  int nn = N >> 7;
  int ntiles = ((rows + 127) >> 7) * nn;
  const u16* B = Bt + (long)e * strideB;
  const float* bvec = bias + (long)e * strideBias;
  __shared__ __align__(16) u16 lA[2][128 * 64];
  __shared__ __align__(16) u16 lB[2][128 * 64];
  int tid = threadIdx.x, lane = tid & 63, w = tid >> 6;   // w in 0..7
  int wr = w >> 2, wc = w & 3;                 // 2M x 4N wave grid
  int l15 = lane & 15, l4 = lane >> 4;
  int lr8 = lane >> 3;                         // 0..7: row within 8-row group
  int csrc = ((lane & 7) ^ lr8) * 8;           // inverse-swizzled src chunk (shorts)
  int nt = K >> 6;

  for (int t = slot; t < ntiles; t += 256) {
    int rbk = t / nn, nb = t - rbk * nn;
    int m0 = r0 + rbk * 128;
    long n0 = (long)nb * 128;
    u32 asrc[2], bsrc[2];
#pragma unroll
    for (int r = 0; r < 2; r++) {
      int row = w * 16 + r * 8 + lr8;
      int g = m0 + row; if (g > r1 - 1) g = r1 - 1;
      int ar = (EPI == 2) ? tlist[g] : g;
      asrc[r] = (u32)ar * (u32)K + csrc;
      bsrc[r] = (u32)(n0 + row) * (u32)K + csrc;
    }
    f32x4 acc[4][2];
    f32x4 zz = {0.0f, 0.0f, 0.0f, 0.0f};
#pragma unroll
    for (int i = 0; i < 4; i++)
#pragma unroll
      for (int j = 0; j < 2; j++) acc[i][j] = zz;

#define STAGE_MOE(buf, k0_) do { u32 o_ = (k0_); \
    _Pragma("unroll") \
    for (int r = 0; r < 2; r++) { \
      gload16(&A[asrc[r] + o_], &lA[buf][(w * 16 + r * 8) * 64]); \
      gload16(&B[bsrc[r] + o_], &lB[buf][(w * 16 + r * 8) * 64]); \
    } } while (0)

    STAGE_MOE(0, 0);
    __syncthreads();
    int cur = 0;
    for (int s = 0; s < nt; s++) {
      if (s + 1 < nt) STAGE_MOE(cur ^ 1, (u32)(s + 1) * 64);
#pragma unroll
      for (int ks = 0; ks < 2; ks++) {
        bf16x8 af[4], bq[2];
#pragma unroll
        for (int mi = 0; mi < 4; mi++) {
          int row = wr * 64 + mi * 16 + l15;
          af[mi] = *(const bf16x8*)&lA[cur][row * 64 + (((ks * 4 + l4) ^ (l15 & 7)) * 8)];
        }
#pragma unroll
        for (int ni = 0; ni < 2; ni++) {
          int row = wc * 32 + ni * 16 + l15;
          bq[ni] = *(const bf16x8*)&lB[cur][row * 64 + (((ks * 4 + l4) ^ (l15 & 7)) * 8)];
        }
#pragma unroll
        for (int mi = 0; mi < 4; mi++)
#pragma unroll
          for (int ni = 0; ni < 2; ni++)
            acc[mi][ni] = __builtin_amdgcn_mfma_f32_16x16x32_bf16(af[mi], bq[ni], acc[mi][ni], 0, 0, 0);
      }
      __syncthreads();
      cur ^= 1;
    }
#undef STAGE_MOE
#pragma unroll
    for (int mi = 0; mi < 4; mi++) {
#pragma unroll
      for (int j = 0; j < 4; j++) {
        int row = m0 + wr * 64 + mi * 16 + l4 * 4 + j;
        if (row < r1) {
#pragma unroll
          for (int ni = 0; ni < 2; ni++) {
            long col = n0 + wc * 32 + ni * 16 + l15;
            float vv = acc[mi][ni][j] + bvec[col];
            if (EPI == 2) {
              ((u16*)Cout)[(long)row * N + col] = f2b(gelu_exact(vv));
            } else {
              ((float*)Cout)[(long)row * N + col] = vv;
            }
          }
        }
      }
    }
  }
}

// ---------------- combine: out = x1 + w0*oute[s0] + w1*oute[s1] -----------
__global__ __launch_bounds__(256) void k_combine(
    const float* __restrict__ x1, const float* __restrict__ oute,
    const int* __restrict__ slot_of, const float* __restrict__ wts,
    float* __restrict__ out)
{
  int t = blockIdx.x;
  int c = threadIdx.x * 4;
  int s0 = slot_of[2 * t], s1 = slot_of[2 * t + 1];
  float w0 = wts[2 * t], w1 = wts[2 * t + 1];
  float4 a  = *(const float4*)&x1[(long)t * 1024 + c];
  float4 e0 = *(const float4*)&oute[(long)s0 * 1024 + c];
  float4 e1 = *(const float4*)&oute[(long)s1 * 1024 + c];
  float4 r;
  r.x = a.x + w0 * e0.x + w1 * e1.x;
  r.y = a.y + w0 * e0.y + w1 * e1.y;
  r.z = a.z + w0 * e0.z + w1 * e1.z;
  r.w = a.w + w0 * e0.w + w1 * e1.w;
  *(float4*)&out[(long)t * 1024 + c] = r;
}

// ===========================================================================
extern "C" void kernel_launch(void* const* d_in, const int* in_sizes, int n_in,
                              void* d_out, int out_size, void* d_ws, size_t ws_size,
                              hipStream_t stream)
{
  const float* x    = (const float*)d_in[0];
  const float* ln1s = (const float*)d_in[2];
  const float* ln1b = (const float*)d_in[3];
  const float* Wq   = (const float*)d_in[4];
  const float* Wdkv = (const float*)d_in[5];
  const float* Wukv = (const float*)d_in[6];
  const float* Wo   = (const float*)d_in[7];
  const float* ln2s = (const float*)d_in[8];
  const float* ln2b = (const float*)d_in[9];
  const float* Wg   = (const float*)d_in[10];
  const float* bg   = (const float*)d_in[11];
  const float* We1  = (const float*)d_in[12];
  const float* be1  = (const float*)d_in[13];
  const float* We2  = (const float*)d_in[14];
  const float* be2  = (const float*)d_in[15];
  float* out = (float*)d_out;

  char* wp = (char*)d_ws;
  auto take = [&](size_t nbytes) -> void* {
    char* r = wp; wp += (nbytes + 255) & ~(size_t)255; return (void*)r;
  };
  u16* We1t = (u16*)take(8L * 2048 * 1024 * 2);
  u16* We2t = (u16*)take(8L * 1024 * 2048 * 2);
  u16* hh   = (u16*)take(4096L * 1024 * 2);
  u16* hl   = (u16*)take(4096L * 1024 * 2);
  u16* qh   = (u16*)take(4096L * 1024 * 2);
  u16* ql   = (u16*)take(4096L * 1024 * 2);
  u16* kvh  = (u16*)take(4096L * 1024 * 2);
  u16* kvl  = (u16*)take(4096L * 1024 * 2);
  u16* kvTh = (u16*)take(4096L * 1024 * 2);
  u16* kvTl = (u16*)take(4096L * 1024 * 2);
  u16* cbh  = (u16*)take(4096L * 512 * 2);
  u16* cbl  = (u16*)take(4096L * 512 * 2);
  float* x1 = (float*)take(4096L * 1024 * 4);
  u16* hid  = (u16*)take(8192L * 2048 * 2);
  int*   sel   = (int*)take(8192 * 4);
  float* wts   = (float*)take(8192 * 4);
  int*   cnt   = (int*)take(64);
  int*   offs  = (int*)take(64);
  int*   tlist = (int*)take(8192 * 4);
  int*   slot  = (int*)take(8192 * 4);
  // phase-based aliases (lifetimes disjoint on the in-order stream):
  u16* attn_h = hh;                 // hh/hl dead after Wq+Wdkv GEMMs
  u16* attn_l = hl;
  u16* h2bf   = cbh;                // spans cbh+cbl (dead after kv-up GEMM)
  float* oute = (float*)qh;         // spans qh+ql (dead after flash)
  float* Pk   = (float*)We2t;       // split-K partials (32 MB); We2 transposed AFTER
  // split attention weights live in `hid` (dead until k_gemm_moe<2>): 12 MB
  u16* Wqh   = hid;
  u16* Wql   = Wqh   + 1024L * 1024;
  u16* Wdkvh = Wql   + 1024L * 1024;
  u16* Wdkvl = Wdkvh + 512L * 1024;
  u16* Wukvh = Wdkvl + 512L * 1024;
  u16* Wukvl = Wukvh + 1024L * 512;
  u16* Woh   = Wukvl + 1024L * 512;
  u16* Wol   = Woh   + 1024L * 1024;
  if ((size_t)(wp - (char*)d_ws) > ws_size) return;

  dim3 b256(256), b512(512);
  // attention weights -> split hi/lo bf16, K-major
  k_split_transpose<<<dim3(16, 16), b256, 0, stream>>>(Wq,   Wqh,   Wql,   1024, 1024);
  k_split_transpose<<<dim3(8, 16),  b256, 0, stream>>>(Wdkv, Wdkvh, Wdkvl, 1024, 512);
  k_split_transpose<<<dim3(16, 8),  b256, 0, stream>>>(Wukv, Wukvh, Wukvl, 512, 1024);
  k_split_transpose<<<dim3(16, 16), b256, 0, stream>>>(Wo,   Woh,   Wol,   1024, 1024);
  // attention path (split-bf16 MFMA + split-K2, fp32-equivalent accuracy)
  k_layernorm<2><<<dim3(4096), b256, 0, stream>>>(x, ln1s, ln1b, hh, hl);
  k_gemm_bf3<<<dim3(512), b256, 0, stream>>>(hh, hl, Wqh, Wql, Pk, 4096, 1024, 1024);
  k_red_split<<<dim3(4096), b256, 0, stream>>>(Pk, qh, ql, 4096L * 1024);
  k_gemm_bf3<<<dim3(256), b256, 0, stream>>>(hh, hl, Wdkvh, Wdkvl, Pk, 4096, 512, 1024);
  k_red_split<<<dim3(2048), b256, 0, stream>>>(Pk, cbh, cbl, 4096L * 512);
  k_gemm_bf3<<<dim3(512), b256, 0, stream>>>(cbh, cbl, Wukvh, Wukvl, Pk, 4096, 1024, 512);
  k_red_kv<<<dim3(32, 32), b256, 0, stream>>>(Pk, kvh, kvl, kvTh, kvTl);
  k_flash_v3<<<dim3(32, 32), b256, 0, stream>>>(qh, ql, kvh, kvl, kvTh, kvTl, attn_h, attn_l);
  k_gemm_bf3<<<dim3(512), b256, 0, stream>>>(attn_h, attn_l, Woh, Wol, Pk, 4096, 1024, 1024);
  k_red_resid<<<dim3(4096), b256, 0, stream>>>(Pk, x, x1, 4096L * 1024);
  // MoE
  k_layernorm<1><<<dim3(4096), b256, 0, stream>>>(x1, ln2s, ln2b, h2bf, nullptr);
  k_gate<<<dim3(1024), b256, 0, stream>>>(x1, ln2s, ln2b, Wg, bg, sel, wts);
  k_count<<<dim3(8), b256, 0, stream>>>(sel, cnt);
  k_offsets<<<dim3(1), dim3(64), 0, stream>>>(cnt, offs);
  k_scatter<<<dim3(8), b256, 0, stream>>>(sel, offs, tlist, slot);
  // expert weights -> bf16, K-major (after Pk is dead: Pk aliases We2t)
  k_transpose_bf16<<<dim3(32, 16, 8), b256, 0, stream>>>(We1, We1t, 1024, 2048);
  k_transpose_bf16<<<dim3(16, 32, 8), b256, 0, stream>>>(We2, We2t, 2048, 1024);
  k_gemm_moe<2><<<dim3(2048), b512, 0, stream>>>(h2bf, We1t, hid, be1, tlist, offs,
                                                 2048, 1024, 2048L * 1024, 2048);
  k_gemm_moe<3><<<dim3(2048), b512, 0, stream>>>(hid, We2t, oute, be2, tlist, offs,
                                                 1024, 2048, 1024L * 2048, 1024);
  k_combine<<<dim3(4096), b256, 0, stream>>>(x1, oute, slot, wts, out);
}